// Round 5
// baseline (546.760 us; speedup 1.0000x reference)
//
#include <hip/hip_runtime.h>
#include <hip/hip_bf16.h>
#include <stdint.h>
#include <stddef.h>

// ---------- types ----------
typedef __attribute__((ext_vector_type(8))) short bf16x8;          // 8 bf16 in 4 VGPRs
typedef __attribute__((ext_vector_type(8))) unsigned short u16x8;  // 16B vector
typedef __attribute__((ext_vector_type(4))) float f32x4;

#define MFMA16(a, b, c) __builtin_amdgcn_mfma_f32_16x16x32_bf16((a), (b), (c), 0, 0, 0)

__device__ __forceinline__ unsigned short f2b(float f) {  // f32 -> bf16 RNE
  union { float f; unsigned u; } v; v.f = f;
  unsigned r = v.u + 0x7fffu + ((v.u >> 16) & 1u);
  return (unsigned short)(r >> 16);
}
__device__ __forceinline__ float b2f(unsigned short h) {
  union { unsigned u; float f; } v; v.u = ((unsigned)h) << 16;
  return v.f;
}

__device__ __forceinline__ void gload_lds16(const void* g, void* l) {
  __builtin_amdgcn_global_load_lds((const __attribute__((address_space(1))) void*)g,
                                   (__attribute__((address_space(3))) void*)l, 16, 0, 0);
}

// ---------- transpose + convert f32 (K x N) -> bf16 (N x K) ----------
__global__ void k_transpose_f32_bf16(const float* __restrict__ in,
                                     unsigned short* __restrict__ out,
                                     int K, int N) {
  __shared__ float tile[64][65];
  const int kb = blockIdx.x * 64;
  const int nb = blockIdx.y * 64;
  const int t = threadIdx.x;          // 256
  const int c4 = (t & 15) * 4;
  const int rr = t >> 4;              // 0..15
#pragma unroll
  for (int i = 0; i < 4; ++i) {
    int r = rr + i * 16;
    float4 v = *reinterpret_cast<const float4*>(in + (size_t)(kb + r) * N + nb + c4);
    tile[r][c4 + 0] = v.x; tile[r][c4 + 1] = v.y;
    tile[r][c4 + 2] = v.z; tile[r][c4 + 3] = v.w;
  }
  __syncthreads();
#pragma unroll
  for (int i = 0; i < 4; ++i) {
    int n = rr + i * 16;
    ushort4 w;
    w.x = f2b(tile[c4 + 0][n]); w.y = f2b(tile[c4 + 1][n]);
    w.z = f2b(tile[c4 + 2][n]); w.w = f2b(tile[c4 + 3][n]);
    *reinterpret_cast<ushort4*>(out + (size_t)(nb + n) * K + kb + c4) = w;
  }
}

// ---------- elementwise f32 -> bf16 ----------
__global__ void k_f32_to_bf16(const float* __restrict__ in, unsigned short* __restrict__ out) {
  size_t i = ((size_t)blockIdx.x * blockDim.x + threadIdx.x) * 4;
  float4 v = *reinterpret_cast<const float4*>(in + i);
  ushort4 w; w.x = f2b(v.x); w.y = f2b(v.y); w.z = f2b(v.z); w.w = f2b(v.w);
  *reinterpret_cast<ushort4*>(out + i) = w;
}

// ---------- GEMM: C[M,N] = A[M,K] (bf16, row-major) * Bt[N,K]^T (bf16, K-major) ----------
template <bool OUT_F32>
__global__ void __launch_bounds__(256, 2)
k_gemm(const unsigned short* __restrict__ A, const unsigned short* __restrict__ Bt,
       void* __restrict__ C, int M, int N, int K) {
  __shared__ unsigned short As[128 * 32];
  __shared__ unsigned short Bs[128 * 32];
  const int m0 = blockIdx.x * 128;
  const int n0 = blockIdx.y * 128;
  const int tid = threadIdx.x;
  const int lane = tid & 63;
  const int w = tid >> 6;
  const int wr = w >> 1, wc = w & 1;
  const int cl = lane & 15, rg = lane >> 4;
  const int ko = rg * 8;

  f32x4 acc[4][4] = {};

  for (int k0 = 0; k0 < K; k0 += 32) {
#pragma unroll
    for (int i = 0; i < 2; ++i) {
      int c = i * 256 + tid;
      gload_lds16(A + (size_t)(m0 + (c >> 2)) * K + k0 + (c & 3) * 8, As + c * 8);
    }
#pragma unroll
    for (int i = 0; i < 2; ++i) {
      int c = i * 256 + tid;
      gload_lds16(Bt + (size_t)(n0 + (c >> 2)) * K + k0 + (c & 3) * 8, Bs + c * 8);
    }
    __syncthreads();
    bf16x8 a[4], b[4];
#pragma unroll
    for (int mi = 0; mi < 4; ++mi)
      a[mi] = *reinterpret_cast<const bf16x8*>(As + (wr * 64 + mi * 16 + cl) * 32 + ko);
#pragma unroll
    for (int ni = 0; ni < 4; ++ni)
      b[ni] = *reinterpret_cast<const bf16x8*>(Bs + (wc * 64 + ni * 16 + cl) * 32 + ko);
#pragma unroll
    for (int mi = 0; mi < 4; ++mi)
#pragma unroll
      for (int ni = 0; ni < 4; ++ni)
        acc[mi][ni] = MFMA16(a[mi], b[ni], acc[mi][ni]);
    __syncthreads();
  }
#pragma unroll
  for (int mi = 0; mi < 4; ++mi)
#pragma unroll
    for (int ni = 0; ni < 4; ++ni) {
      int row = m0 + wr * 64 + mi * 16 + rg * 4;
      int col = n0 + wc * 64 + ni * 16 + cl;
#pragma unroll
      for (int r = 0; r < 4; ++r) {
        float v = acc[mi][ni][r];
        if (OUT_F32) ((float*)C)[(size_t)(row + r) * N + col] = v;
        else         ((unsigned short*)C)[(size_t)(row + r) * N + col] = f2b(v);
      }
    }
}

// ---------- RoPE + reshape: Cpre[S,6144] -> Qr[H,S,DH] (pre-scaled), Kr[KV,S,DH] ----------
__global__ void k_rope(const unsigned short* __restrict__ Cpre,
                       const float* __restrict__ cosb, const float* __restrict__ sinb,
                       unsigned short* __restrict__ Qr, unsigned short* __restrict__ Kr) {
  const int s = blockIdx.x;
  const int hh = blockIdx.y;      // 0-31 q heads, 32-39 k heads
  const int d = threadIdx.x;      // 0..127
  const int col = (hh < 32) ? hh * 128 + d : 4096 + (hh - 32) * 128 + d;
  float t = b2f(Cpre[(size_t)s * 6144 + col]);
  const int dp = (d < 64) ? d + 64 : d - 64;
  float tp = b2f(Cpre[(size_t)s * 6144 + (col - d + dp)]);
  float rot = (d < 64) ? -tp : tp;
  float o = t * cosb[s * 128 + d] + rot * sinb[s * 128 + d];
  if (hh < 32) {
    Qr[((size_t)hh * 2048 + s) * 128 + d] = f2b(o * 0.08838834764831845f);
  } else {
    Kr[((size_t)(hh - 32) * 2048 + s) * 128 + d] = f2b(o);
  }
}

// ---------- V transpose: Cpre[S, 5120 + kv*128 + d] -> Vt[KV, DH, S] ----------
__global__ void k_transpose_v(const unsigned short* __restrict__ Cpre,
                              unsigned short* __restrict__ Vt) {
  __shared__ unsigned short tile[64][72];
  const int sb = blockIdx.x * 64;
  const int db = blockIdx.y * 64;
  const int kv = blockIdx.z;
  const int t = threadIdx.x;
#pragma unroll
  for (int i = 0; i < 2; ++i) {
    int sl = i * 32 + (t >> 3);
    int d8 = (t & 7) * 8;
    const unsigned short* src = Cpre + (size_t)(sb + sl) * 6144 + 5120 + kv * 128 + db + d8;
    ushort4 v0 = *reinterpret_cast<const ushort4*>(src);
    ushort4 v1 = *reinterpret_cast<const ushort4*>(src + 4);
    *reinterpret_cast<ushort4*>(&tile[sl][d8]) = v0;
    *reinterpret_cast<ushort4*>(&tile[sl][d8 + 4]) = v1;
  }
  __syncthreads();
#pragma unroll
  for (int i = 0; i < 2; ++i) {
    int dl = i * 32 + (t >> 3);
    int s8 = (t & 7) * 8;
    ushort4 w0, w1;
    w0.x = tile[s8 + 0][dl]; w0.y = tile[s8 + 1][dl]; w0.z = tile[s8 + 2][dl]; w0.w = tile[s8 + 3][dl];
    w1.x = tile[s8 + 4][dl]; w1.y = tile[s8 + 5][dl]; w1.z = tile[s8 + 6][dl]; w1.w = tile[s8 + 7][dl];
    unsigned short* dst = Vt + ((size_t)kv * 128 + db + dl) * 2048 + sb + s8;
    *reinterpret_cast<ushort4*>(dst) = w0;
    *reinterpret_cast<ushort4*>(dst + 4) = w1;
  }
}

// ---------- fused causal GQA flash attention (v5) ----------
// Barrier-free: K/V MFMA fragments are 8 contiguous bf16 in global (K=[s][d],
// Vt=[d][s]) -> each lane loads them directly; L1/L2 do the tile sharing
// (per-kv-head K+V = 1MB, L2-resident, XCD-aligned via bid&7). No K/V LDS,
// no __syncthreads, waves fully independent. LDS = Ps only (8KB, wave-private).
#define QBLK 64
__global__ void __launch_bounds__(256, 3)
k_attn(const unsigned short* __restrict__ Qr, const unsigned short* __restrict__ Kr,
       const unsigned short* __restrict__ Vt, unsigned short* __restrict__ ctx) {
  __shared__ unsigned short Ps[64 * 64];    // [q_local][kv_local] swizzled, 8KB
  const int bid = blockIdx.x;
  const int kv = bid & 7;                   // XCD-aligned kv head
  const int h  = kv * 4 + ((bid >> 3) & 3);
  const int qb = 31 - (bid >> 5);           // heavy-first
  const int q0 = qb * QBLK;
  const int tid = threadIdx.x;
  const int lane = tid & 63;
  const int w = tid >> 6;
  const int cl = lane & 15, rg = lane >> 4;

  const unsigned short* Kbase = Kr + (size_t)kv * 2048 * 128;
  const unsigned short* Vbase = Vt + (size_t)kv * 128 * 2048;

  // Q fragments: rows q0 + w*16 + cl, k = kk*32 + rg*8  (Q pre-scaled by 1/sqrt(d))
  bf16x8 qf[4];
#pragma unroll
  for (int kk = 0; kk < 4; ++kk)
    qf[kk] = *reinterpret_cast<const bf16x8*>(
        Qr + ((size_t)h * 2048 + q0 + w * 16 + cl) * 128 + kk * 32 + rg * 8);

  f32x4 po[8] = {};
  float mrow[4], lrow[4];
#pragma unroll
  for (int r = 0; r < 4; ++r) { mrow[r] = -1e30f; lrow[r] = 0.f; }

  const int jmax = qb + 1;
  for (int j = 0; j < jmax; ++j) {
    const unsigned short* Kj = Kbase + (size_t)j * 64 * 128;
    const unsigned short* Vj = Vbase + (size_t)j * 64;

    // S = Q K^T : B-fragments loaded straight from global (8 contiguous bf16)
    f32x4 sa[4] = {};
#pragma unroll
    for (int ni = 0; ni < 4; ++ni) {
      bf16x8 kf[4];
#pragma unroll
      for (int kk = 0; kk < 4; ++kk)
        kf[kk] = *reinterpret_cast<const bf16x8*>(
            Kj + (size_t)(ni * 16 + cl) * 128 + kk * 32 + rg * 8);
      __builtin_amdgcn_s_setprio(1);
#pragma unroll
      for (int kk = 0; kk < 4; ++kk)
        sa[ni] = MFMA16(qf[kk], kf[kk], sa[ni]);
      __builtin_amdgcn_s_setprio(0);
    }

    // causal mask: only the diagonal tile (j == qb) has masked entries
    if (j == qb) {
      int qbase = w * 16 + rg * 4;
#pragma unroll
      for (int ni = 0; ni < 4; ++ni) {
        int kcol = ni * 16 + cl;
#pragma unroll
        for (int r = 0; r < 4; ++r)
          if (kcol > qbase + r) sa[ni][r] = -1e30f;
      }
    }

    // online softmax (row lives in the 16 lanes sharing rg)
#pragma unroll
    for (int r = 0; r < 4; ++r) {
      float t = fmaxf(fmaxf(sa[0][r], sa[1][r]), fmaxf(sa[2][r], sa[3][r]));
      t = fmaxf(t, __shfl_xor(t, 1));
      t = fmaxf(t, __shfl_xor(t, 2));
      t = fmaxf(t, __shfl_xor(t, 4));
      t = fmaxf(t, __shfl_xor(t, 8));
      float mnew = fmaxf(mrow[r], t);
      float sf = __expf(mrow[r] - mnew);
      mrow[r] = mnew;
#pragma unroll
      for (int di = 0; di < 8; ++di) po[di][r] *= sf;
      float rs = 0.f;
#pragma unroll
      for (int ni = 0; ni < 4; ++ni) {
        float p = __expf(sa[ni][r] - mnew);
        sa[ni][r] = p;
        rs += p;
      }
      rs += __shfl_xor(rs, 1);
      rs += __shfl_xor(rs, 2);
      rs += __shfl_xor(rs, 4);
      rs += __shfl_xor(rs, 8);
      lrow[r] = lrow[r] * sf + rs;
    }

    // write P (wave-private 16-row slab; in-wave LDS ordering only, no barrier)
#pragma unroll
    for (int ni = 0; ni < 4; ++ni)
#pragma unroll
      for (int r = 0; r < 4; ++r) {
        int prow = w * 16 + rg * 4 + r;
        int off = (prow * 128 + (ni * 16 + cl) * 2) ^ ((prow & 7) << 4);
        *(unsigned short*)((char*)Ps + off) = f2b(sa[ni][r]);
      }
    asm volatile("s_waitcnt lgkmcnt(0)" ::: "memory");
    __builtin_amdgcn_sched_barrier(0);

    // O += P V : V B-fragments straight from global (8 contiguous bf16 in s)
#pragma unroll
    for (int kk = 0; kk < 2; ++kk) {
      int prow = w * 16 + cl;
      int poff = (prow * 128 + (kk * 32 + rg * 8) * 2) ^ ((prow & 7) << 4);
      bf16x8 pa = *reinterpret_cast<const bf16x8*>((const char*)Ps + poff);
      bf16x8 vb[8];
#pragma unroll
      for (int di = 0; di < 8; ++di)
        vb[di] = *reinterpret_cast<const bf16x8*>(
            Vj + (size_t)(di * 16 + cl) * 2048 + kk * 32 + rg * 8);
      __builtin_amdgcn_s_setprio(1);
#pragma unroll
      for (int di = 0; di < 8; ++di)
        po[di] = MFMA16(pa, vb[di], po[di]);
      __builtin_amdgcn_s_setprio(0);
    }
  }

  // epilogue: normalize, write ctx[s][h*128+d]
#pragma unroll
  for (int r = 0; r < 4; ++r) {
    float inv = 1.0f / lrow[r];
    int srow = q0 + w * 16 + rg * 4 + r;
#pragma unroll
    for (int di = 0; di < 8; ++di)
      ctx[(size_t)srow * 4096 + h * 128 + di * 16 + cl] = f2b(po[di][r] * inv);
  }
}

// ---------- launch ----------
extern "C" void kernel_launch(void* const* d_in, const int* in_sizes, int n_in,
                              void* d_out, int out_size, void* d_ws, size_t ws_size,
                              hipStream_t stream) {
  const float* X    = (const float*)d_in[0];
  const float* cosb = (const float*)d_in[2];
  const float* sinb = (const float*)d_in[3];
  const float* Wq   = (const float*)d_in[4];
  const float* Wk   = (const float*)d_in[5];
  const float* Wv   = (const float*)d_in[6];
  const float* Wo   = (const float*)d_in[7];

  char* ws = (char*)d_ws;
  unsigned short* WT   = (unsigned short*)(ws + 0);           // 6144x4096 bf16 (later: WoT)
  unsigned short* Xb   = (unsigned short*)(ws + 50331648ull); // 2048x4096 bf16
  unsigned short* Cpre = (unsigned short*)(ws + 67108864ull); // 2048x6144 bf16 (later: ctx)
  unsigned short* Qr   = (unsigned short*)(ws + 92274688ull); // 32x2048x128 bf16
  unsigned short* Kr   = (unsigned short*)(ws + 109051904ull);// 8x2048x128 bf16
  unsigned short* Vt   = (unsigned short*)(ws + 113246208ull);// 8x128x2048 bf16
  unsigned short* ctx  = Cpre;

  k_transpose_f32_bf16<<<dim3(64, 64), 256, 0, stream>>>(Wq, WT, 4096, 4096);
  k_transpose_f32_bf16<<<dim3(64, 16), 256, 0, stream>>>(Wk, WT + (size_t)4096 * 4096, 4096, 1024);
  k_transpose_f32_bf16<<<dim3(64, 16), 256, 0, stream>>>(Wv, WT + (size_t)5120 * 4096, 4096, 1024);
  k_f32_to_bf16<<<8192, 256, 0, stream>>>(X, Xb);

  k_gemm<false><<<dim3(16, 48), 256, 0, stream>>>(Xb, WT, Cpre, 2048, 6144, 4096);

  k_rope<<<dim3(2048, 40), 128, 0, stream>>>(Cpre, cosb, sinb, Qr, Kr);
  k_transpose_v<<<dim3(32, 2, 8), 256, 0, stream>>>(Cpre, Vt);

  k_transpose_f32_bf16<<<dim3(64, 64), 256, 0, stream>>>(Wo, WT, 4096, 4096);

  k_attn<<<1024, 256, 0, stream>>>(Qr, Kr, Vt, ctx);

  k_gemm<true><<<dim3(16, 32), 256, 0, stream>>>(ctx, WT, d_out, 2048, 4096, 4096);
}

// Round 6
// 501.850 us; speedup vs baseline: 1.0895x; 1.0895x over previous
//
#include <hip/hip_runtime.h>
#include <hip/hip_bf16.h>
#include <stdint.h>
#include <stddef.h>

// ---------- types ----------
typedef __attribute__((ext_vector_type(8))) short bf16x8;          // 8 bf16 in 4 VGPRs
typedef __attribute__((ext_vector_type(8))) unsigned short u16x8;  // 16B vector
typedef __attribute__((ext_vector_type(4))) float f32x4;

#define MFMA16(a, b, c) __builtin_amdgcn_mfma_f32_16x16x32_bf16((a), (b), (c), 0, 0, 0)

__device__ __forceinline__ unsigned short f2b(float f) {  // f32 -> bf16 RNE
  union { float f; unsigned u; } v; v.f = f;
  unsigned r = v.u + 0x7fffu + ((v.u >> 16) & 1u);
  return (unsigned short)(r >> 16);
}
__device__ __forceinline__ float b2f(unsigned short h) {
  union { unsigned u; float f; } v; v.u = ((unsigned)h) << 16;
  return v.f;
}

__device__ __forceinline__ void gload_lds16(const void* g, void* l) {
  __builtin_amdgcn_global_load_lds((const __attribute__((address_space(1))) void*)g,
                                   (__attribute__((address_space(3))) void*)l, 16, 0, 0);
}

// ---------- transpose + convert f32 (K x N) -> bf16 (N x K) ----------
__global__ void k_transpose_f32_bf16(const float* __restrict__ in,
                                     unsigned short* __restrict__ out,
                                     int K, int N) {
  __shared__ float tile[64][65];
  const int kb = blockIdx.x * 64;
  const int nb = blockIdx.y * 64;
  const int t = threadIdx.x;          // 256
  const int c4 = (t & 15) * 4;
  const int rr = t >> 4;              // 0..15
#pragma unroll
  for (int i = 0; i < 4; ++i) {
    int r = rr + i * 16;
    float4 v = *reinterpret_cast<const float4*>(in + (size_t)(kb + r) * N + nb + c4);
    tile[r][c4 + 0] = v.x; tile[r][c4 + 1] = v.y;
    tile[r][c4 + 2] = v.z; tile[r][c4 + 3] = v.w;
  }
  __syncthreads();
#pragma unroll
  for (int i = 0; i < 4; ++i) {
    int n = rr + i * 16;
    ushort4 w;
    w.x = f2b(tile[c4 + 0][n]); w.y = f2b(tile[c4 + 1][n]);
    w.z = f2b(tile[c4 + 2][n]); w.w = f2b(tile[c4 + 3][n]);
    *reinterpret_cast<ushort4*>(out + (size_t)(nb + n) * K + kb + c4) = w;
  }
}

// ---------- elementwise f32 -> bf16 ----------
__global__ void k_f32_to_bf16(const float* __restrict__ in, unsigned short* __restrict__ out) {
  size_t i = ((size_t)blockIdx.x * blockDim.x + threadIdx.x) * 4;
  float4 v = *reinterpret_cast<const float4*>(in + i);
  ushort4 w; w.x = f2b(v.x); w.y = f2b(v.y); w.z = f2b(v.z); w.w = f2b(v.w);
  *reinterpret_cast<ushort4*>(out + i) = w;
}

// ---------- deep-pipelined GEMM: C[M,N] = A[M,K] * Bt[N,K]^T ----------
// 256 x (NFRAG*64) tile, BK=64, 512 threads (8 waves, 2M x 4N), 2 LDS buffers,
// counted vmcnt (never 0 in loop), XOR-swizzled LDS via pre-swizzled global src.
// Grid is exactly 256 blocks (8 M-panels x 32 N-panels), XCD-aware mapping.
template <int NFRAG, bool OUT_F32>
__global__ void __launch_bounds__(512, 2)
k_gemm8(const unsigned short* __restrict__ A, const unsigned short* __restrict__ Bt,
        void* __restrict__ C, int M, int N, int K) {
  constexpr int BN = NFRAG * 64;
  constexpr int BLOADS = BN / 64;              // B gload issues per thread per tile
  __shared__ unsigned short As[2][256 * 64];   // [buf][row*64 + col]
  __shared__ unsigned short Bs[2][BN * 64];

  const int tid = threadIdx.x;
  const int l  = tid & 63;
  const int wv = tid >> 6;         // 0..7
  const int wm = wv >> 2;          // 0..1
  const int wn = wv & 3;           // 0..3
  const int cl = l & 15, rg = l >> 4;

  // XCD-aware block mapping: 8 XCDs x 32 blocks; 4 N-panels per XCD
  const int x   = blockIdx.x & 7;
  const int idx = blockIdx.x >> 3;             // 0..31
  const int bn  = x * 4 + (idx & 3);           // 0..31
  const int bm  = idx >> 2;                    // 0..7
  const int m0  = bm * 256;
  const int n0  = bn * BN;

  // staging geometry: each gload covers an 8-row x 128B window per wave
  const int srow = l >> 3;                     // row within window (0..7)
  const int scol = ((l & 7) ^ srow) * 8;       // pre-swizzled source col (elems)

  f32x4 acc[8][NFRAG] = {};
  const int nt = K >> 6;

#define STAGE_A(i, t, cbuf)                                                     \
  { int w_idx = (i) * 8 + wv;                                                   \
    gload_lds16(A + (size_t)(m0 + w_idx * 8 + srow) * K + (t) * 64 + scol,      \
                &As[cbuf][w_idx * 512 + l * 8]); }

#define STAGE_B(j, t, cbuf)                                                     \
  { int w_idx = (j) * 8 + wv;                                                   \
    gload_lds16(Bt + (size_t)(n0 + w_idx * 8 + srow) * K + (t) * 64 + scol,     \
                &Bs[cbuf][w_idx * 512 + l * 8]); }

  // phase P: mi = 2P, 2P+1 ; uses bfr[][] (B frags, read once per tile)
#define PHASE(P, cbuf)                                                          \
  {                                                                             \
    bf16x8 a[2][2];                                                             \
    _Pragma("unroll")                                                           \
    for (int im = 0; im < 2; ++im) {                                            \
      const int row = wm * 128 + (2 * (P) + im) * 16 + cl;                      \
      a[im][0] = *reinterpret_cast<const bf16x8*>(                              \
          &As[cbuf][row * 64 + ((rg ^ (cl & 7)) * 8)]);                         \
      a[im][1] = *reinterpret_cast<const bf16x8*>(                              \
          &As[cbuf][row * 64 + (((4 + rg) ^ (cl & 7)) * 8)]);                   \
    }                                                                           \
    __builtin_amdgcn_s_setprio(1);                                              \
    _Pragma("unroll")                                                           \
    for (int im = 0; im < 2; ++im)                                              \
      _Pragma("unroll")                                                         \
      for (int ni = 0; ni < NFRAG; ++ni) {                                      \
        acc[2 * (P) + im][ni] = MFMA16(a[im][0], bfr[ni][0], acc[2 * (P) + im][ni]); \
        acc[2 * (P) + im][ni] = MFMA16(a[im][1], bfr[ni][1], acc[2 * (P) + im][ni]); \
      }                                                                         \
    __builtin_amdgcn_s_setprio(0);                                              \
  }

  // ---- prologue: stage tile 0 fully, drain once ----
#pragma unroll
  for (int j = 0; j < BLOADS; ++j) STAGE_B(j, 0, 0);
#pragma unroll
  for (int i = 0; i < 4; ++i) STAGE_A(i, 0, 0);
  asm volatile("s_waitcnt vmcnt(0)" ::: "memory");
  __builtin_amdgcn_sched_barrier(0);
  __builtin_amdgcn_s_barrier();
  __builtin_amdgcn_sched_barrier(0);

  for (int t = 0; t < nt; ++t) {
    const int c  = t & 1;
    const int cn = c ^ 1;
    const int tn = (t + 1 < nt) ? t + 1 : t;   // clamp: uniform vmcnt counts

    // stage B(t+1)
#pragma unroll
    for (int j = 0; j < BLOADS; ++j) STAGE_B(j, tn, cn);
    __builtin_amdgcn_sched_barrier(0);

    // B fragments for tile t (rows wn*NFRAG*16 .. +NFRAG*16-1)
    bf16x8 bfr[NFRAG][2];
#pragma unroll
    for (int ni = 0; ni < NFRAG; ++ni) {
      const int row = wn * (NFRAG * 16) + ni * 16 + cl;
      bfr[ni][0] = *reinterpret_cast<const bf16x8*>(
          &Bs[c][row * 64 + ((rg ^ (cl & 7)) * 8)]);
      bfr[ni][1] = *reinterpret_cast<const bf16x8*>(
          &Bs[c][row * 64 + (((4 + rg) ^ (cl & 7)) * 8)]);
    }

    PHASE(0, c)                       // mi 0,1  (A rows 0-31 / 128-159: A0,A2)
    STAGE_A(0, tn, cn); STAGE_A(2, tn, cn);
    __builtin_amdgcn_sched_barrier(0);
    PHASE(1, c)                       // mi 2,3  (A0,A2)

    // mid barrier: publish A1,A3 of tile t (issued last iter); keep t+1's
    // B (BLOADS) + A0,A2 (2) in flight
    if constexpr (BLOADS == 3) { asm volatile("s_waitcnt vmcnt(5)" ::: "memory"); }
    else                       { asm volatile("s_waitcnt vmcnt(4)" ::: "memory"); }
    __builtin_amdgcn_sched_barrier(0);
    __builtin_amdgcn_s_barrier();
    __builtin_amdgcn_sched_barrier(0);

    STAGE_A(1, tn, cn); STAGE_A(3, tn, cn);
    __builtin_amdgcn_sched_barrier(0);
    PHASE(2, c)                       // mi 4,5  (A1,A3)
    PHASE(3, c)                       // mi 6,7  (A1,A3)

    // end barrier: publish B,A0,A2 of tile t+1; keep A1,A3 (2) in flight
    asm volatile("s_waitcnt vmcnt(2)" ::: "memory");
    __builtin_amdgcn_sched_barrier(0);
    __builtin_amdgcn_s_barrier();
    __builtin_amdgcn_sched_barrier(0);
  }

#undef STAGE_A
#undef STAGE_B
#undef PHASE

  // epilogue: C/D layout col = lane&15, row = (lane>>4)*4 + reg
#pragma unroll
  for (int mi = 0; mi < 8; ++mi)
#pragma unroll
    for (int ni = 0; ni < NFRAG; ++ni) {
      const int row = m0 + wm * 128 + mi * 16 + rg * 4;
      const int col = n0 + wn * (NFRAG * 16) + ni * 16 + cl;
#pragma unroll
      for (int r = 0; r < 4; ++r) {
        float v = acc[mi][ni][r];
        if (OUT_F32) ((float*)C)[(size_t)(row + r) * N + col] = v;
        else         ((unsigned short*)C)[(size_t)(row + r) * N + col] = f2b(v);
      }
    }
}

// ---------- RoPE + reshape: Cpre[S,6144] -> Qr[H,S,DH] (pre-scaled), Kr[KV,S,DH] ----------
__global__ void k_rope(const unsigned short* __restrict__ Cpre,
                       const float* __restrict__ cosb, const float* __restrict__ sinb,
                       unsigned short* __restrict__ Qr, unsigned short* __restrict__ Kr) {
  const int s = blockIdx.x;
  const int hh = blockIdx.y;      // 0-31 q heads, 32-39 k heads
  const int d = threadIdx.x;      // 0..127
  const int col = (hh < 32) ? hh * 128 + d : 4096 + (hh - 32) * 128 + d;
  float t = b2f(Cpre[(size_t)s * 6144 + col]);
  const int dp = (d < 64) ? d + 64 : d - 64;
  float tp = b2f(Cpre[(size_t)s * 6144 + (col - d + dp)]);
  float rot = (d < 64) ? -tp : tp;
  float o = t * cosb[s * 128 + d] + rot * sinb[s * 128 + d];
  if (hh < 32) {
    Qr[((size_t)hh * 2048 + s) * 128 + d] = f2b(o * 0.08838834764831845f);
  } else {
    Kr[((size_t)(hh - 32) * 2048 + s) * 128 + d] = f2b(o);
  }
}

// ---------- V transpose: Cpre[S, 5120 + kv*128 + d] -> Vt[KV, DH, S] ----------
__global__ void k_transpose_v(const unsigned short* __restrict__ Cpre,
                              unsigned short* __restrict__ Vt) {
  __shared__ unsigned short tile[64][72];
  const int sb = blockIdx.x * 64;
  const int db = blockIdx.y * 64;
  const int kv = blockIdx.z;
  const int t = threadIdx.x;
#pragma unroll
  for (int i = 0; i < 2; ++i) {
    int sl = i * 32 + (t >> 3);
    int d8 = (t & 7) * 8;
    const unsigned short* src = Cpre + (size_t)(sb + sl) * 6144 + 5120 + kv * 128 + db + d8;
    ushort4 v0 = *reinterpret_cast<const ushort4*>(src);
    ushort4 v1 = *reinterpret_cast<const ushort4*>(src + 4);
    *reinterpret_cast<ushort4*>(&tile[sl][d8]) = v0;
    *reinterpret_cast<ushort4*>(&tile[sl][d8 + 4]) = v1;
  }
  __syncthreads();
#pragma unroll
  for (int i = 0; i < 2; ++i) {
    int dl = i * 32 + (t >> 3);
    int s8 = (t & 7) * 8;
    ushort4 w0, w1;
    w0.x = tile[s8 + 0][dl]; w0.y = tile[s8 + 1][dl]; w0.z = tile[s8 + 2][dl]; w0.w = tile[s8 + 3][dl];
    w1.x = tile[s8 + 4][dl]; w1.y = tile[s8 + 5][dl]; w1.z = tile[s8 + 6][dl]; w1.w = tile[s8 + 7][dl];
    unsigned short* dst = Vt + ((size_t)kv * 128 + db + dl) * 2048 + sb + s8;
    *reinterpret_cast<ushort4*>(dst) = w0;
    *reinterpret_cast<ushort4*>(dst + 4) = w1;
  }
}

// ---------- fused causal GQA flash attention (R4 version: best measured) ----------
#define QBLK 64
#define KVBLK 64
__global__ void __launch_bounds__(256, 3)
k_attn(const unsigned short* __restrict__ Qr, const unsigned short* __restrict__ Kr,
       const unsigned short* __restrict__ Vt, unsigned short* __restrict__ ctx) {
  __shared__ unsigned short Ks[64 * 128];   // [kv_local][d]  swizzled, 16KB
  __shared__ unsigned short Vs[128 * 64];   // [d][kv_local]  swizzled, 16KB
  __shared__ unsigned short Ps[64 * 64];    // [q_local][kv_local] swizzled, 8KB
  const int bid = blockIdx.x;
  const int kv = bid & 7;                   // XCD-aligned kv head
  const int h  = kv * 4 + ((bid >> 3) & 3);
  const int qb = 31 - (bid >> 5);           // heavy-first
  const int q0 = qb * QBLK;
  const int tid = threadIdx.x;
  const int lane = tid & 63;
  const int w = tid >> 6;
  const int cl = lane & 15, rg = lane >> 4;

  const unsigned short* Kbase = Kr + (size_t)kv * 2048 * 128;
  const unsigned short* Vbase = Vt + (size_t)kv * 128 * 2048;

  // Q fragments: rows q0 + w*16 + cl, k = kk*32 + rg*8  (Q pre-scaled by 1/sqrt(d))
  bf16x8 qf[4];
#pragma unroll
  for (int kk = 0; kk < 4; ++kk)
    qf[kk] = *reinterpret_cast<const bf16x8*>(
        Qr + ((size_t)h * 2048 + q0 + w * 16 + cl) * 128 + kk * 32 + rg * 8);

  f32x4 po[8] = {};
  float mrow[4], lrow[4];
#pragma unroll
  for (int r = 0; r < 4; ++r) { mrow[r] = -1e30f; lrow[r] = 0.f; }

  // staging geometry
  const int krr = tid >> 4;             // 0..15
  const int kcc = (tid & 15) * 8;
  const int vrr = tid >> 3;             // 0..31
  const int vcc = (tid & 7) * 8;

  // prologue: prefetch tile 0 into registers
  u16x8 kst[4], vst[4];
#pragma unroll
  for (int i = 0; i < 4; ++i)
    kst[i] = *reinterpret_cast<const u16x8*>(Kbase + (size_t)(i * 16 + krr) * 128 + kcc);
#pragma unroll
  for (int i = 0; i < 4; ++i)
    vst[i] = *reinterpret_cast<const u16x8*>(Vbase + (size_t)(i * 32 + vrr) * 2048 + vcc);

  const int jmax = qb + 1;
  for (int j = 0; j < jmax; ++j) {
    // barrier A: all waves done reading previous tile's LDS
    asm volatile("" ::: "memory");
    __builtin_amdgcn_s_barrier();
    asm volatile("" ::: "memory");
    // staged regs -> LDS (swizzled)
#pragma unroll
    for (int i = 0; i < 4; ++i) {
      int row = i * 16 + krr;
      int off = (row * 256 + kcc * 2) ^ ((row & 7) << 4);
      *reinterpret_cast<u16x8*>((char*)Ks + off) = kst[i];
    }
#pragma unroll
    for (int i = 0; i < 4; ++i) {
      int row = i * 32 + vrr;
      int off = (row * 128 + vcc * 2) ^ ((row & 7) << 4);
      *reinterpret_cast<u16x8*>((char*)Vs + off) = vst[i];
    }
    // issue prefetch for next tile (stays in flight across compute)
    const int jn = (j + 1 < jmax) ? j + 1 : j;
#pragma unroll
    for (int i = 0; i < 4; ++i)
      kst[i] = *reinterpret_cast<const u16x8*>(
          Kbase + (size_t)(jn * 64 + i * 16 + krr) * 128 + kcc);
#pragma unroll
    for (int i = 0; i < 4; ++i)
      vst[i] = *reinterpret_cast<const u16x8*>(
          Vbase + (size_t)(i * 32 + vrr) * 2048 + jn * 64 + vcc);
    // barrier B: LDS writes visible; vmcnt NOT drained
    asm volatile("s_waitcnt lgkmcnt(0)" ::: "memory");
    __builtin_amdgcn_s_barrier();
    asm volatile("" ::: "memory");

    // S = Q K^T : rows = 16 q of this wave, cols = 64 kv
    f32x4 sa[4] = {};
    __builtin_amdgcn_s_setprio(1);
#pragma unroll
    for (int ni = 0; ni < 4; ++ni)
#pragma unroll
      for (int kk = 0; kk < 4; ++kk) {
        int row = ni * 16 + cl;
        int off = (row * 256 + (kk * 32 + rg * 8) * 2) ^ ((row & 7) << 4);
        bf16x8 bfr = *reinterpret_cast<const bf16x8*>((const char*)Ks + off);
        sa[ni] = MFMA16(qf[kk], bfr, sa[ni]);
      }
    __builtin_amdgcn_s_setprio(0);

    // causal mask: only the diagonal tile (j == jmax-1) has masked entries
    if (j == jmax - 1) {
      int qbase = w * 16 + rg * 4;
#pragma unroll
      for (int ni = 0; ni < 4; ++ni) {
        int kcol = ni * 16 + cl;
#pragma unroll
        for (int r = 0; r < 4; ++r)
          if (kcol > qbase + r) sa[ni][r] = -1e30f;
      }
    }

    // online softmax (row lives in the 16 lanes sharing rg)
#pragma unroll
    for (int r = 0; r < 4; ++r) {
      float t = fmaxf(fmaxf(sa[0][r], sa[1][r]), fmaxf(sa[2][r], sa[3][r]));
      t = fmaxf(t, __shfl_xor(t, 1));
      t = fmaxf(t, __shfl_xor(t, 2));
      t = fmaxf(t, __shfl_xor(t, 4));
      t = fmaxf(t, __shfl_xor(t, 8));
      float mnew = fmaxf(mrow[r], t);
      float sf = __expf(mrow[r] - mnew);
      mrow[r] = mnew;
#pragma unroll
      for (int di = 0; di < 8; ++di) po[di][r] *= sf;
      float rs = 0.f;
#pragma unroll
      for (int ni = 0; ni < 4; ++ni) {
        float p = __expf(sa[ni][r] - mnew);
        sa[ni][r] = p;
        rs += p;
      }
      rs += __shfl_xor(rs, 1);
      rs += __shfl_xor(rs, 2);
      rs += __shfl_xor(rs, 4);
      rs += __shfl_xor(rs, 8);
      lrow[r] = lrow[r] * sf + rs;
    }

    // write P (wave-private 16-row slab; in-wave LDS ordering only)
#pragma unroll
    for (int ni = 0; ni < 4; ++ni)
#pragma unroll
      for (int r = 0; r < 4; ++r) {
        int prow = w * 16 + rg * 4 + r;
        int off = (prow * 128 + (ni * 16 + cl) * 2) ^ ((prow & 7) << 4);
        *(unsigned short*)((char*)Ps + off) = f2b(sa[ni][r]);
      }
    asm volatile("s_waitcnt lgkmcnt(0)" ::: "memory");
    __builtin_amdgcn_sched_barrier(0);

    // O += P V
    __builtin_amdgcn_s_setprio(1);
#pragma unroll
    for (int kk = 0; kk < 2; ++kk) {
      int prow = w * 16 + cl;
      int poff = (prow * 128 + (kk * 32 + rg * 8) * 2) ^ ((prow & 7) << 4);
      bf16x8 pa = *reinterpret_cast<const bf16x8*>((const char*)Ps + poff);
#pragma unroll
      for (int di = 0; di < 8; ++di) {
        int vrow = di * 16 + cl;
        int voff = (vrow * 128 + (kk * 32 + rg * 8) * 2) ^ ((vrow & 7) << 4);
        bf16x8 vb = *reinterpret_cast<const bf16x8*>((const char*)Vs + voff);
        po[di] = MFMA16(pa, vb, po[di]);
      }
    }
    __builtin_amdgcn_s_setprio(0);
  }

  // epilogue: normalize, write ctx[s][h*128+d]
#pragma unroll
  for (int r = 0; r < 4; ++r) {
    float inv = 1.0f / lrow[r];
    int srow = q0 + w * 16 + rg * 4 + r;
#pragma unroll
    for (int di = 0; di < 8; ++di)
      ctx[(size_t)srow * 4096 + h * 128 + di * 16 + cl] = f2b(po[di][r] * inv);
  }
}

// ---------- launch ----------
extern "C" void kernel_launch(void* const* d_in, const int* in_sizes, int n_in,
                              void* d_out, int out_size, void* d_ws, size_t ws_size,
                              hipStream_t stream) {
  const float* X    = (const float*)d_in[0];
  const float* cosb = (const float*)d_in[2];
  const float* sinb = (const float*)d_in[3];
  const float* Wq   = (const float*)d_in[4];
  const float* Wk   = (const float*)d_in[5];
  const float* Wv   = (const float*)d_in[6];
  const float* Wo   = (const float*)d_in[7];

  char* ws = (char*)d_ws;
  unsigned short* WT   = (unsigned short*)(ws + 0);           // 6144x4096 bf16 (later: WoT)
  unsigned short* Xb   = (unsigned short*)(ws + 50331648ull); // 2048x4096 bf16
  unsigned short* Cpre = (unsigned short*)(ws + 67108864ull); // 2048x6144 bf16 (later: ctx)
  unsigned short* Qr   = (unsigned short*)(ws + 92274688ull); // 32x2048x128 bf16
  unsigned short* Kr   = (unsigned short*)(ws + 109051904ull);// 8x2048x128 bf16
  unsigned short* Vt   = (unsigned short*)(ws + 113246208ull);// 8x128x2048 bf16
  unsigned short* ctx  = Cpre;

  k_transpose_f32_bf16<<<dim3(64, 64), 256, 0, stream>>>(Wq, WT, 4096, 4096);
  k_transpose_f32_bf16<<<dim3(64, 16), 256, 0, stream>>>(Wk, WT + (size_t)4096 * 4096, 4096, 1024);
  k_transpose_f32_bf16<<<dim3(64, 16), 256, 0, stream>>>(Wv, WT + (size_t)5120 * 4096, 4096, 1024);
  k_f32_to_bf16<<<8192, 256, 0, stream>>>(X, Xb);

  // fused QKV projection: (2048 x 4096) @ (4096 x 6144), 256x192 tiles
  k_gemm8<3, false><<<256, 512, 0, stream>>>(Xb, WT, Cpre, 2048, 6144, 4096);

  k_rope<<<dim3(2048, 40), 128, 0, stream>>>(Cpre, cosb, sinb, Qr, Kr);
  k_transpose_v<<<dim3(32, 2, 8), 256, 0, stream>>>(Cpre, Vt);

  k_transpose_f32_bf16<<<dim3(64, 64), 256, 0, stream>>>(Wo, WT, 4096, 4096);

  k_attn<<<1024, 256, 0, stream>>>(Qr, Kr, Vt, ctx);

  // out projection: (2048 x 4096) @ (4096 x 4096), 256x128 tiles -> f32
  k_gemm8<2, true><<<256, 512, 0, stream>>>(ctx, WT, d_out, 2048, 4096, 4096);
}

// Round 7
// 367.517 us; speedup vs baseline: 1.4877x; 1.3655x over previous
//
#include <hip/hip_runtime.h>
#include <hip/hip_bf16.h>
#include <stdint.h>
#include <stddef.h>

// ---------- types ----------
typedef __attribute__((ext_vector_type(8))) short bf16x8;          // 8 bf16 in 4 VGPRs
typedef __attribute__((ext_vector_type(8))) unsigned short u16x8;  // 16B vector
typedef __attribute__((ext_vector_type(4))) float f32x4;
typedef __attribute__((ext_vector_type(16))) float f32x16;

#define MFMA16(a, b, c) __builtin_amdgcn_mfma_f32_16x16x32_bf16((a), (b), (c), 0, 0, 0)
#define MFMA32(a, b, c) __builtin_amdgcn_mfma_f32_32x32x16_bf16((a), (b), (c), 0, 0, 0)

__device__ __forceinline__ unsigned short f2b(float f) {  // f32 -> bf16 RNE
  union { float f; unsigned u; } v; v.f = f;
  unsigned r = v.u + 0x7fffu + ((v.u >> 16) & 1u);
  return (unsigned short)(r >> 16);
}
__device__ __forceinline__ float b2f(unsigned short h) {
  union { unsigned u; float f; } v; v.u = ((unsigned)h) << 16;
  return v.f;
}

__device__ __forceinline__ void gload_lds16(const void* g, void* l) {
  __builtin_amdgcn_global_load_lds((const __attribute__((address_space(1))) void*)g,
                                   (__attribute__((address_space(3))) void*)l, 16, 0, 0);
}

// ---------- transpose + convert f32 (K x N) -> bf16 (N x K) ----------
__global__ void k_transpose_f32_bf16(const float* __restrict__ in,
                                     unsigned short* __restrict__ out,
                                     int K, int N) {
  __shared__ float tile[64][65];
  const int kb = blockIdx.x * 64;
  const int nb = blockIdx.y * 64;
  const int t = threadIdx.x;          // 256
  const int c4 = (t & 15) * 4;
  const int rr = t >> 4;              // 0..15
#pragma unroll
  for (int i = 0; i < 4; ++i) {
    int r = rr + i * 16;
    float4 v = *reinterpret_cast<const float4*>(in + (size_t)(kb + r) * N + nb + c4);
    tile[r][c4 + 0] = v.x; tile[r][c4 + 1] = v.y;
    tile[r][c4 + 2] = v.z; tile[r][c4 + 3] = v.w;
  }
  __syncthreads();
#pragma unroll
  for (int i = 0; i < 4; ++i) {
    int n = rr + i * 16;
    ushort4 w;
    w.x = f2b(tile[c4 + 0][n]); w.y = f2b(tile[c4 + 1][n]);
    w.z = f2b(tile[c4 + 2][n]); w.w = f2b(tile[c4 + 3][n]);
    *reinterpret_cast<ushort4*>(out + (size_t)(nb + n) * K + kb + c4) = w;
  }
}

// ---------- elementwise f32 -> bf16 ----------
__global__ void k_f32_to_bf16(const float* __restrict__ in, unsigned short* __restrict__ out) {
  size_t i = ((size_t)blockIdx.x * blockDim.x + threadIdx.x) * 4;
  float4 v = *reinterpret_cast<const float4*>(in + i);
  ushort4 w; w.x = f2b(v.x); w.y = f2b(v.y); w.z = f2b(v.z); w.w = f2b(v.w);
  *reinterpret_cast<ushort4*>(out + i) = w;
}

// ---------- GEMM (R4 known-good): C[M,N] = A[M,K] * Bt[N,K]^T ----------
template <bool OUT_F32>
__global__ void __launch_bounds__(256, 2)
k_gemm(const unsigned short* __restrict__ A, const unsigned short* __restrict__ Bt,
       void* __restrict__ C, int M, int N, int K) {
  __shared__ unsigned short As[128 * 32];
  __shared__ unsigned short Bs[128 * 32];
  const int m0 = blockIdx.x * 128;
  const int n0 = blockIdx.y * 128;
  const int tid = threadIdx.x;
  const int lane = tid & 63;
  const int w = tid >> 6;
  const int wr = w >> 1, wc = w & 1;
  const int cl = lane & 15, rg = lane >> 4;
  const int ko = rg * 8;

  f32x4 acc[4][4] = {};

  for (int k0 = 0; k0 < K; k0 += 32) {
#pragma unroll
    for (int i = 0; i < 2; ++i) {
      int c = i * 256 + tid;
      gload_lds16(A + (size_t)(m0 + (c >> 2)) * K + k0 + (c & 3) * 8, As + c * 8);
    }
#pragma unroll
    for (int i = 0; i < 2; ++i) {
      int c = i * 256 + tid;
      gload_lds16(Bt + (size_t)(n0 + (c >> 2)) * K + k0 + (c & 3) * 8, Bs + c * 8);
    }
    __syncthreads();
    bf16x8 a[4], b[4];
#pragma unroll
    for (int mi = 0; mi < 4; ++mi)
      a[mi] = *reinterpret_cast<const bf16x8*>(As + (wr * 64 + mi * 16 + cl) * 32 + ko);
#pragma unroll
    for (int ni = 0; ni < 4; ++ni)
      b[ni] = *reinterpret_cast<const bf16x8*>(Bs + (wc * 64 + ni * 16 + cl) * 32 + ko);
#pragma unroll
    for (int mi = 0; mi < 4; ++mi)
#pragma unroll
      for (int ni = 0; ni < 4; ++ni)
        acc[mi][ni] = MFMA16(a[mi], b[ni], acc[mi][ni]);
    __syncthreads();
  }
#pragma unroll
  for (int mi = 0; mi < 4; ++mi)
#pragma unroll
    for (int ni = 0; ni < 4; ++ni) {
      int row = m0 + wr * 64 + mi * 16 + rg * 4;
      int col = n0 + wc * 64 + ni * 16 + cl;
#pragma unroll
      for (int r = 0; r < 4; ++r) {
        float v = acc[mi][ni][r];
        if (OUT_F32) ((float*)C)[(size_t)(row + r) * N + col] = v;
        else         ((unsigned short*)C)[(size_t)(row + r) * N + col] = f2b(v);
      }
    }
}

// ---------- RoPE + reshape: Cpre[S,6144] -> Qr[H,S,DH] (pre-scaled), Kr[KV,S,DH] ----------
__global__ void k_rope(const unsigned short* __restrict__ Cpre,
                       const float* __restrict__ cosb, const float* __restrict__ sinb,
                       unsigned short* __restrict__ Qr, unsigned short* __restrict__ Kr) {
  const int s = blockIdx.x;
  const int hh = blockIdx.y;      // 0-31 q heads, 32-39 k heads
  const int d = threadIdx.x;      // 0..127
  const int col = (hh < 32) ? hh * 128 + d : 4096 + (hh - 32) * 128 + d;
  float t = b2f(Cpre[(size_t)s * 6144 + col]);
  const int dp = (d < 64) ? d + 64 : d - 64;
  float tp = b2f(Cpre[(size_t)s * 6144 + (col - d + dp)]);
  float rot = (d < 64) ? -tp : tp;
  float o = t * cosb[s * 128 + d] + rot * sinb[s * 128 + d];
  if (hh < 32) {
    Qr[((size_t)hh * 2048 + s) * 128 + d] = f2b(o * 0.08838834764831845f);
  } else {
    Kr[((size_t)(hh - 32) * 2048 + s) * 128 + d] = f2b(o);
  }
}

// ---------- V transpose: Cpre[S, 5120 + kv*128 + d] -> Vt[KV, DH, S] ----------
__global__ void k_transpose_v(const unsigned short* __restrict__ Cpre,
                              unsigned short* __restrict__ Vt) {
  __shared__ unsigned short tile[64][72];
  const int sb = blockIdx.x * 64;
  const int db = blockIdx.y * 64;
  const int kv = blockIdx.z;
  const int t = threadIdx.x;
#pragma unroll
  for (int i = 0; i < 2; ++i) {
    int sl = i * 32 + (t >> 3);
    int d8 = (t & 7) * 8;
    const unsigned short* src = Cpre + (size_t)(sb + sl) * 6144 + 5120 + kv * 128 + db + d8;
    ushort4 v0 = *reinterpret_cast<const ushort4*>(src);
    ushort4 v1 = *reinterpret_cast<const ushort4*>(src + 4);
    *reinterpret_cast<ushort4*>(&tile[sl][d8]) = v0;
    *reinterpret_cast<ushort4*>(&tile[sl][d8 + 4]) = v1;
  }
  __syncthreads();
#pragma unroll
  for (int i = 0; i < 2; ++i) {
    int dl = i * 32 + (t >> 3);
    int s8 = (t & 7) * 8;
    ushort4 w0, w1;
    w0.x = tile[s8 + 0][dl]; w0.y = tile[s8 + 1][dl]; w0.z = tile[s8 + 2][dl]; w0.w = tile[s8 + 3][dl];
    w1.x = tile[s8 + 4][dl]; w1.y = tile[s8 + 5][dl]; w1.z = tile[s8 + 6][dl]; w1.w = tile[s8 + 7][dl];
    unsigned short* dst = Vt + ((size_t)kv * 128 + db + dl) * 2048 + sb + s8;
    *reinterpret_cast<ushort4*>(dst) = w0;
    *reinterpret_cast<ushort4*>(dst + 4) = w1;
  }
}

// ---------- fused causal GQA flash attention (v6: swapped-QK 32x32, in-reg softmax) ----------
// QBLK=128, 4 waves x 32 q-rows. S^T = mfma32(K,Q): lane owns P-row for q=qmap(lane&31).
// Softmax fully in-register (31 fmax tree + 1 shfl); P->B-frag via shfl_xor(32) exchange.
// K/V LDS staged w/ reg-prefetch (R4 pattern); no P LDS. grid 512 (32h x 16qb).
__global__ void __launch_bounds__(256, 2)
k_attn(const unsigned short* __restrict__ Qr, const unsigned short* __restrict__ Kr,
       const unsigned short* __restrict__ Vt, unsigned short* __restrict__ ctx) {
  __shared__ unsigned short Ks[64 * 128];   // [kv][d]  swizzled, 16KB
  __shared__ unsigned short Vs[128 * 64];   // [d][kv]  swizzled, 16KB
  const int bid = blockIdx.x;
  const int kv = bid & 7;                   // XCD-aligned kv head
  const int hd = kv * 4 + ((bid >> 3) & 3);
  const int qb = 15 - (bid >> 5);           // heavy-first
  const int q0 = qb * 128;
  const int tid = threadIdx.x;
  const int l = tid & 63;
  const int w = tid >> 6;
  const int i5 = l & 31;                    // q-col index within wave
  const int h  = l >> 5;                    // lane half
  // interleaved q map: wave covers 16 low + 16 high rows -> uniform jmax across waves
  const int qg = q0 + w * 16 + (i5 & 15) + (i5 >> 4) * 64;

  const unsigned short* Kbase = Kr + (size_t)kv * 2048 * 128;
  const unsigned short* Vbase = Vt + (size_t)kv * 128 * 2048;

  // Q B-fragments: lane -> col q=qg, d-slice s*16 + h*8 (Q pre-scaled by 1/sqrt(d))
  bf16x8 qf[8];
#pragma unroll
  for (int s = 0; s < 8; ++s)
    qf[s] = *reinterpret_cast<const bf16x8*>(
        Qr + ((size_t)hd * 2048 + qg) * 128 + s * 16 + h * 8);

  f32x16 po[4] = {};              // O^T: [dblk], lane col q=qg, rows d
  float mrow = -1e30f, lrow = 0.f;

  // staging geometry (256 threads)
  const int krr = tid >> 4, kcc = (tid & 15) * 8;
  const int vrr = tid >> 3, vcc = (tid & 7) * 8;

  u16x8 kst[4], vst[4];
#pragma unroll
  for (int ii = 0; ii < 4; ++ii)
    kst[ii] = *reinterpret_cast<const u16x8*>(Kbase + (size_t)(ii * 16 + krr) * 128 + kcc);
#pragma unroll
  for (int ii = 0; ii < 4; ++ii)
    vst[ii] = *reinterpret_cast<const u16x8*>(Vbase + (size_t)(ii * 32 + vrr) * 2048 + vcc);

  const int jmax = 2 * qb + 2;
  for (int j = 0; j < jmax; ++j) {
    // barrier A: previous tile's LDS reads done
    asm volatile("" ::: "memory");
    __builtin_amdgcn_s_barrier();
    asm volatile("" ::: "memory");
#pragma unroll
    for (int ii = 0; ii < 4; ++ii) {
      int row = ii * 16 + krr;
      *reinterpret_cast<u16x8*>((char*)Ks + ((row * 256 + kcc * 2) ^ ((row & 7) << 4))) = kst[ii];
    }
#pragma unroll
    for (int ii = 0; ii < 4; ++ii) {
      int row = ii * 32 + vrr;
      *reinterpret_cast<u16x8*>((char*)Vs + ((row * 128 + vcc * 2) ^ ((row & 7) << 4))) = vst[ii];
    }
    const int jn = (j + 1 < jmax) ? j + 1 : j;
#pragma unroll
    for (int ii = 0; ii < 4; ++ii)
      kst[ii] = *reinterpret_cast<const u16x8*>(
          Kbase + (size_t)(jn * 64 + ii * 16 + krr) * 128 + kcc);
#pragma unroll
    for (int ii = 0; ii < 4; ++ii)
      vst[ii] = *reinterpret_cast<const u16x8*>(
          Vbase + (size_t)(ii * 32 + vrr) * 2048 + jn * 64 + vcc);
    // barrier B: LDS visible; vmcnt NOT drained (prefetch in flight)
    asm volatile("s_waitcnt lgkmcnt(0)" ::: "memory");
    __builtin_amdgcn_s_barrier();
    asm volatile("" ::: "memory");

    // S^T[kv][q] = mfma32(A=K rows, B=Q): sa[ni] covers kv ni*32..+32
    f32x16 sa[2] = {};
    __builtin_amdgcn_s_setprio(1);
#pragma unroll
    for (int ni = 0; ni < 2; ++ni) {
      const int row = ni * 32 + i5;
      const int swz = (row & 7) << 4;
#pragma unroll
      for (int s = 0; s < 8; ++s) {
        bf16x8 kf = *reinterpret_cast<const bf16x8*>(
            (const char*)Ks + ((row * 256 + s * 32 + h * 16) ^ swz));
        sa[ni] = MFMA32(kf, qf[s], sa[ni]);
      }
    }
    __builtin_amdgcn_s_setprio(0);

    // causal mask (diagonal region only): kv = j*64 + ni*32 + (r&3)+8*(r>>2)+4h
    if (j >= 2 * qb) {
#pragma unroll
      for (int ni = 0; ni < 2; ++ni) {
        const int kvb = j * 64 + ni * 32 + 4 * h;
#pragma unroll
        for (int r = 0; r < 16; ++r) {
          int kvg = kvb + (r & 3) + 8 * (r >> 2);
          if (kvg > qg) sa[ni][r] = -__builtin_inff();
        }
      }
    }

    // in-lane row max + 1 cross-half shfl
    float pmax = sa[0][0];
#pragma unroll
    for (int r = 1; r < 16; ++r) pmax = fmaxf(pmax, sa[0][r]);
#pragma unroll
    for (int r = 0; r < 16; ++r) pmax = fmaxf(pmax, sa[1][r]);
    pmax = fmaxf(pmax, __shfl_xor(pmax, 32));

    // defer-max rescale (T13, THR=8)
    if (!__all(pmax <= mrow + 8.0f)) {
      float mnew = fmaxf(mrow, pmax);
      float sf = __expf(mrow - mnew);
#pragma unroll
      for (int d = 0; d < 4; ++d)
#pragma unroll
        for (int r = 0; r < 16; ++r) po[d][r] *= sf;
      lrow *= sf;
      mrow = mnew;
    }

    // exp + in-lane sum + 1 shfl
    float rs = 0.f;
#pragma unroll
    for (int ni = 0; ni < 2; ++ni)
#pragma unroll
      for (int r = 0; r < 16; ++r) {
        float p = __expf(sa[ni][r] - mrow);
        sa[ni][r] = p;
        rs += p;
      }
    rs += __shfl_xor(rs, 32);
    lrow += rs;

    // pack P -> PV B-fragments. For ks: kv-slice 16ks + 8h + e.
    // word source: c = 2*(ks&1) + h' ; words 0,1 from h'=0 lane, 2,3 from h'=1.
    bf16x8 pfrag[4];
#pragma unroll
    for (int ni = 0; ni < 2; ++ni) {
      unsigned wd[8];
#pragma unroll
      for (int c = 0; c < 4; ++c)
#pragma unroll
        for (int ii = 0; ii < 2; ++ii)
          wd[c * 2 + ii] = (unsigned)f2b(sa[ni][4 * c + 2 * ii]) |
                           ((unsigned)f2b(sa[ni][4 * c + 2 * ii + 1]) << 16);
#pragma unroll
      for (int k2 = 0; k2 < 2; ++k2) {
        unsigned e0 = wd[(2 * k2) * 2 + 0], e1 = wd[(2 * k2) * 2 + 1];
        unsigned o0 = wd[(2 * k2 + 1) * 2 + 0], o1 = wd[(2 * k2 + 1) * 2 + 1];
        unsigned pe0 = (unsigned)__shfl_xor((int)e0, 32);
        unsigned pe1 = (unsigned)__shfl_xor((int)e1, 32);
        unsigned po0 = (unsigned)__shfl_xor((int)o0, 32);
        unsigned po1 = (unsigned)__shfl_xor((int)o1, 32);
        union { unsigned u[4]; bf16x8 v; } uu;
        uu.u[0] = h ? po0 : e0;
        uu.u[1] = h ? po1 : e1;
        uu.u[2] = h ? o0 : pe0;
        uu.u[3] = h ? o1 : pe1;
        pfrag[ni * 2 + k2] = uu.v;
      }
    }

    // O^T += V^T P^T : po[dblk] = mfma32(A=Vt rows d, B=pfrag[ks])
    __builtin_amdgcn_s_setprio(1);
#pragma unroll
    for (int d = 0; d < 4; ++d) {
      const int row0 = d * 32 + i5;
      const int swz = (row0 & 7) << 4;
#pragma unroll
      for (int ks = 0; ks < 4; ++ks) {
        bf16x8 vf = *reinterpret_cast<const bf16x8*>(
            (const char*)Vs + ((row0 * 128 + ks * 32 + h * 16) ^ swz));
        po[d] = MFMA32(vf, pfrag[ks], po[d]);
      }
    }
    __builtin_amdgcn_s_setprio(0);
  }

  // epilogue: normalize (lrow is per-lane = per-q), write ctx[q][hd*128+d]
  const float inv = 1.0f / lrow;
#pragma unroll
  for (int d = 0; d < 4; ++d)
#pragma unroll
    for (int c = 0; c < 4; ++c) {
      ushort4 st;
      st.x = f2b(po[d][4 * c + 0] * inv);
      st.y = f2b(po[d][4 * c + 1] * inv);
      st.z = f2b(po[d][4 * c + 2] * inv);
      st.w = f2b(po[d][4 * c + 3] * inv);
      *reinterpret_cast<ushort4*>(
          ctx + (size_t)qg * 4096 + hd * 128 + d * 32 + 8 * c + 4 * h) = st;
    }
}

// ---------- launch ----------
extern "C" void kernel_launch(void* const* d_in, const int* in_sizes, int n_in,
                              void* d_out, int out_size, void* d_ws, size_t ws_size,
                              hipStream_t stream) {
  const float* X    = (const float*)d_in[0];
  const float* cosb = (const float*)d_in[2];
  const float* sinb = (const float*)d_in[3];
  const float* Wq   = (const float*)d_in[4];
  const float* Wk   = (const float*)d_in[5];
  const float* Wv   = (const float*)d_in[6];
  const float* Wo   = (const float*)d_in[7];

  char* ws = (char*)d_ws;
  unsigned short* WT   = (unsigned short*)(ws + 0);           // 6144x4096 bf16 (later: WoT)
  unsigned short* Xb   = (unsigned short*)(ws + 50331648ull); // 2048x4096 bf16
  unsigned short* Cpre = (unsigned short*)(ws + 67108864ull); // 2048x6144 bf16 (later: ctx)
  unsigned short* Qr   = (unsigned short*)(ws + 92274688ull); // 32x2048x128 bf16
  unsigned short* Kr   = (unsigned short*)(ws + 109051904ull);// 8x2048x128 bf16
  unsigned short* Vt   = (unsigned short*)(ws + 113246208ull);// 8x128x2048 bf16
  unsigned short* ctx  = Cpre;

  k_transpose_f32_bf16<<<dim3(64, 64), 256, 0, stream>>>(Wq, WT, 4096, 4096);
  k_transpose_f32_bf16<<<dim3(64, 16), 256, 0, stream>>>(Wk, WT + (size_t)4096 * 4096, 4096, 1024);
  k_transpose_f32_bf16<<<dim3(64, 16), 256, 0, stream>>>(Wv, WT + (size_t)5120 * 4096, 4096, 1024);
  k_f32_to_bf16<<<8192, 256, 0, stream>>>(X, Xb);

  k_gemm<false><<<dim3(16, 48), 256, 0, stream>>>(Xb, WT, Cpre, 2048, 6144, 4096);

  k_rope<<<dim3(2048, 40), 128, 0, stream>>>(Cpre, cosb, sinb, Qr, Kr);
  k_transpose_v<<<dim3(32, 2, 8), 256, 0, stream>>>(Cpre, Vt);

  k_transpose_f32_bf16<<<dim3(64, 64), 256, 0, stream>>>(Wo, WT, 4096, 4096);

  k_attn<<<512, 256, 0, stream>>>(Qr, Kr, Vt, ctx);

  k_gemm<true><<<dim3(16, 32), 256, 0, stream>>>(ctx, WT, d_out, 2048, 4096, 4096);
}

// Round 9
// 357.300 us; speedup vs baseline: 1.5303x; 1.0286x over previous
//
#include <hip/hip_runtime.h>
#include <hip/hip_bf16.h>
#include <stdint.h>
#include <stddef.h>

// ---------- types ----------
typedef __attribute__((ext_vector_type(8))) short bf16x8;          // 8 bf16 in 4 VGPRs
typedef __attribute__((ext_vector_type(8))) unsigned short u16x8;  // 16B vector
typedef __attribute__((ext_vector_type(4))) float f32x4;
typedef __attribute__((ext_vector_type(16))) float f32x16;

#define MFMA16(a, b, c) __builtin_amdgcn_mfma_f32_16x16x32_bf16((a), (b), (c), 0, 0, 0)
#define MFMA32(a, b, c) __builtin_amdgcn_mfma_f32_32x32x16_bf16((a), (b), (c), 0, 0, 0)

__device__ __forceinline__ unsigned short f2b(float f) {  // f32 -> bf16 RNE
  union { float f; unsigned u; } v; v.f = f;
  unsigned r = v.u + 0x7fffu + ((v.u >> 16) & 1u);
  return (unsigned short)(r >> 16);
}
__device__ __forceinline__ float b2f(unsigned short h) {
  union { unsigned u; float f; } v; v.u = ((unsigned)h) << 16;
  return v.f;
}

__device__ __forceinline__ void gload_lds16(const void* g, void* l) {
  __builtin_amdgcn_global_load_lds((const __attribute__((address_space(1))) void*)g,
                                   (__attribute__((address_space(3))) void*)l, 16, 0, 0);
}

// ---------- transpose + convert f32 (K x N) -> bf16 (N x K) ----------
__global__ void k_transpose_f32_bf16(const float* __restrict__ in,
                                     unsigned short* __restrict__ out,
                                     int K, int N) {
  __shared__ float tile[64][65];
  const int kb = blockIdx.x * 64;
  const int nb = blockIdx.y * 64;
  const int t = threadIdx.x;          // 256
  const int c4 = (t & 15) * 4;
  const int rr = t >> 4;              // 0..15
#pragma unroll
  for (int i = 0; i < 4; ++i) {
    int r = rr + i * 16;
    float4 v = *reinterpret_cast<const float4*>(in + (size_t)(kb + r) * N + nb + c4);
    tile[r][c4 + 0] = v.x; tile[r][c4 + 1] = v.y;
    tile[r][c4 + 2] = v.z; tile[r][c4 + 3] = v.w;
  }
  __syncthreads();
#pragma unroll
  for (int i = 0; i < 4; ++i) {
    int n = rr + i * 16;
    ushort4 w;
    w.x = f2b(tile[c4 + 0][n]); w.y = f2b(tile[c4 + 1][n]);
    w.z = f2b(tile[c4 + 2][n]); w.w = f2b(tile[c4 + 3][n]);
    *reinterpret_cast<ushort4*>(out + (size_t)(nb + n) * K + kb + c4) = w;
  }
}

// ---------- elementwise f32 -> bf16 ----------
__global__ void k_f32_to_bf16(const float* __restrict__ in, unsigned short* __restrict__ out) {
  size_t i = ((size_t)blockIdx.x * blockDim.x + threadIdx.x) * 4;
  float4 v = *reinterpret_cast<const float4*>(in + i);
  ushort4 w; w.x = f2b(v.x); w.y = f2b(v.y); w.z = f2b(v.z); w.w = f2b(v.w);
  *reinterpret_cast<ushort4*>(out + i) = w;
}

// ---------- GEMM (m97 known-good + T1 XCD swizzle): C[M,N] = A[M,K] * Bt[N,K]^T ----------
// 1D grid (%8==0, bijective): xcd = bid&7; within an XCD the m-panel varies
// fastest so each XCD keeps few B-panels hot in its private L2.
template <bool OUT_F32>
__global__ void __launch_bounds__(256, 2)
k_gemm(const unsigned short* __restrict__ A, const unsigned short* __restrict__ Bt,
       void* __restrict__ C, int M, int N, int K) {
  __shared__ unsigned short As[128 * 32];
  __shared__ unsigned short Bs[128 * 32];
  const int nbm = M >> 7;
  const int per = ((M >> 7) * (N >> 7)) >> 3;   // blocks per XCD
  const int wg  = (blockIdx.x & 7) * per + (blockIdx.x >> 3);
  const int m0 = (wg % nbm) * 128;
  const int n0 = (wg / nbm) * 128;
  const int tid = threadIdx.x;
  const int lane = tid & 63;
  const int w = tid >> 6;
  const int wr = w >> 1, wc = w & 1;
  const int cl = lane & 15, rg = lane >> 4;
  const int ko = rg * 8;

  f32x4 acc[4][4] = {};

  for (int k0 = 0; k0 < K; k0 += 32) {
#pragma unroll
    for (int i = 0; i < 2; ++i) {
      int c = i * 256 + tid;
      gload_lds16(A + (size_t)(m0 + (c >> 2)) * K + k0 + (c & 3) * 8, As + c * 8);
    }
#pragma unroll
    for (int i = 0; i < 2; ++i) {
      int c = i * 256 + tid;
      gload_lds16(Bt + (size_t)(n0 + (c >> 2)) * K + k0 + (c & 3) * 8, Bs + c * 8);
    }
    __syncthreads();
    bf16x8 a[4], b[4];
#pragma unroll
    for (int mi = 0; mi < 4; ++mi)
      a[mi] = *reinterpret_cast<const bf16x8*>(As + (wr * 64 + mi * 16 + cl) * 32 + ko);
#pragma unroll
    for (int ni = 0; ni < 4; ++ni)
      b[ni] = *reinterpret_cast<const bf16x8*>(Bs + (wc * 64 + ni * 16 + cl) * 32 + ko);
#pragma unroll
    for (int mi = 0; mi < 4; ++mi)
#pragma unroll
      for (int ni = 0; ni < 4; ++ni)
        acc[mi][ni] = MFMA16(a[mi], b[ni], acc[mi][ni]);
    __syncthreads();
  }
#pragma unroll
  for (int mi = 0; mi < 4; ++mi)
#pragma unroll
    for (int ni = 0; ni < 4; ++ni) {
      int row = m0 + wr * 64 + mi * 16 + rg * 4;
      int col = n0 + wc * 64 + ni * 16 + cl;
#pragma unroll
      for (int r = 0; r < 4; ++r) {
        float v = acc[mi][ni][r];
        if (OUT_F32) ((float*)C)[(size_t)(row + r) * N + col] = v;
        else         ((unsigned short*)C)[(size_t)(row + r) * N + col] = f2b(v);
      }
    }
}

// ---------- RoPE + reshape: Cpre[S,6144] -> Qr[H,S,DH] (pre-scaled), Kr[KV,S,DH] ----------
// 256-thread blocks, 2 heads per block (halves dispatch count vs 128-thread version)
__global__ void k_rope(const unsigned short* __restrict__ Cpre,
                       const float* __restrict__ cosb, const float* __restrict__ sinb,
                       unsigned short* __restrict__ Qr, unsigned short* __restrict__ Kr) {
  const int s = blockIdx.x;
  const int hh = blockIdx.y * 2 + (threadIdx.x >> 7);  // 0..39: 0-31 q, 32-39 k
  const int d = threadIdx.x & 127;                      // 0..127
  const int col = (hh < 32) ? hh * 128 + d : 4096 + (hh - 32) * 128 + d;
  float t = b2f(Cpre[(size_t)s * 6144 + col]);
  const int dp = (d < 64) ? d + 64 : d - 64;
  float tp = b2f(Cpre[(size_t)s * 6144 + (col - d + dp)]);
  float rot = (d < 64) ? -tp : tp;
  float o = t * cosb[s * 128 + d] + rot * sinb[s * 128 + d];
  if (hh < 32) {
    Qr[((size_t)hh * 2048 + s) * 128 + d] = f2b(o * 0.08838834764831845f);
  } else {
    Kr[((size_t)(hh - 32) * 2048 + s) * 128 + d] = f2b(o);
  }
}

// ---------- V transpose: Cpre[S, 5120 + kv*128 + d] -> Vt[KV, DH, S] ----------
__global__ void k_transpose_v(const unsigned short* __restrict__ Cpre,
                              unsigned short* __restrict__ Vt) {
  __shared__ unsigned short tile[64][72];
  const int sb = blockIdx.x * 64;
  const int db = blockIdx.y * 64;
  const int kv = blockIdx.z;
  const int t = threadIdx.x;
#pragma unroll
  for (int i = 0; i < 2; ++i) {
    int sl = i * 32 + (t >> 3);
    int d8 = (t & 7) * 8;
    const unsigned short* src = Cpre + (size_t)(sb + sl) * 6144 + 5120 + kv * 128 + db + d8;
    ushort4 v0 = *reinterpret_cast<const ushort4*>(src);
    ushort4 v1 = *reinterpret_cast<const ushort4*>(src + 4);
    *reinterpret_cast<ushort4*>(&tile[sl][d8]) = v0;
    *reinterpret_cast<ushort4*>(&tile[sl][d8 + 4]) = v1;
  }
  __syncthreads();
#pragma unroll
  for (int i = 0; i < 2; ++i) {
    int dl = i * 32 + (t >> 3);
    int s8 = (t & 7) * 8;
    ushort4 w0, w1;
    w0.x = tile[s8 + 0][dl]; w0.y = tile[s8 + 1][dl]; w0.z = tile[s8 + 2][dl]; w0.w = tile[s8 + 3][dl];
    w1.x = tile[s8 + 4][dl]; w1.y = tile[s8 + 5][dl]; w1.z = tile[s8 + 6][dl]; w1.w = tile[s8 + 7][dl];
    unsigned short* dst = Vt + ((size_t)kv * 128 + db + dl) * 2048 + sb + s8;
    *reinterpret_cast<ushort4*>(dst) = w0;
    *reinterpret_cast<ushort4*>(dst + 4) = w1;
  }
}

// ---------- fused causal GQA flash attention (R7: swapped-QK 32x32, in-reg softmax) ----------
__global__ void __launch_bounds__(256, 2)
k_attn(const unsigned short* __restrict__ Qr, const unsigned short* __restrict__ Kr,
       const unsigned short* __restrict__ Vt, unsigned short* __restrict__ ctx) {
  __shared__ unsigned short Ks[64 * 128];   // [kv][d]  swizzled, 16KB
  __shared__ unsigned short Vs[128 * 64];   // [d][kv]  swizzled, 16KB
  const int bid = blockIdx.x;
  const int kv = bid & 7;                   // XCD-aligned kv head
  const int hd = kv * 4 + ((bid >> 3) & 3);
  const int qb = 15 - (bid >> 5);           // heavy-first
  const int q0 = qb * 128;
  const int tid = threadIdx.x;
  const int l = tid & 63;
  const int w = tid >> 6;
  const int i5 = l & 31;                    // q-col index within wave
  const int h  = l >> 5;                    // lane half
  const int qg = q0 + w * 16 + (i5 & 15) + (i5 >> 4) * 64;

  const unsigned short* Kbase = Kr + (size_t)kv * 2048 * 128;
  const unsigned short* Vbase = Vt + (size_t)kv * 128 * 2048;

  bf16x8 qf[8];
#pragma unroll
  for (int s = 0; s < 8; ++s)
    qf[s] = *reinterpret_cast<const bf16x8*>(
        Qr + ((size_t)hd * 2048 + qg) * 128 + s * 16 + h * 8);

  f32x16 po[4] = {};
  float mrow = -1e30f, lrow = 0.f;

  const int krr = tid >> 4, kcc = (tid & 15) * 8;
  const int vrr = tid >> 3, vcc = (tid & 7) * 8;

  u16x8 kst[4], vst[4];
#pragma unroll
  for (int ii = 0; ii < 4; ++ii)
    kst[ii] = *reinterpret_cast<const u16x8*>(Kbase + (size_t)(ii * 16 + krr) * 128 + kcc);
#pragma unroll
  for (int ii = 0; ii < 4; ++ii)
    vst[ii] = *reinterpret_cast<const u16x8*>(Vbase + (size_t)(ii * 32 + vrr) * 2048 + vcc);

  const int jmax = 2 * qb + 2;
  for (int j = 0; j < jmax; ++j) {
    asm volatile("" ::: "memory");
    __builtin_amdgcn_s_barrier();
    asm volatile("" ::: "memory");
#pragma unroll
    for (int ii = 0; ii < 4; ++ii) {
      int row = ii * 16 + krr;
      *reinterpret_cast<u16x8*>((char*)Ks + ((row * 256 + kcc * 2) ^ ((row & 7) << 4))) = kst[ii];
    }
#pragma unroll
    for (int ii = 0; ii < 4; ++ii) {
      int row = ii * 32 + vrr;
      *reinterpret_cast<u16x8*>((char*)Vs + ((row * 128 + vcc * 2) ^ ((row & 7) << 4))) = vst[ii];
    }
    const int jn = (j + 1 < jmax) ? j + 1 : j;
#pragma unroll
    for (int ii = 0; ii < 4; ++ii)
      kst[ii] = *reinterpret_cast<const u16x8*>(
          Kbase + (size_t)(jn * 64 + ii * 16 + krr) * 128 + kcc);
#pragma unroll
    for (int ii = 0; ii < 4; ++ii)
      vst[ii] = *reinterpret_cast<const u16x8*>(
          Vbase + (size_t)(ii * 32 + vrr) * 2048 + jn * 64 + vcc);
    asm volatile("s_waitcnt lgkmcnt(0)" ::: "memory");
    __builtin_amdgcn_s_barrier();
    asm volatile("" ::: "memory");

    f32x16 sa[2] = {};
    __builtin_amdgcn_s_setprio(1);
#pragma unroll
    for (int ni = 0; ni < 2; ++ni) {
      const int row = ni * 32 + i5;
      const int swz = (row & 7) << 4;
#pragma unroll
      for (int s = 0; s < 8; ++s) {
        bf16x8 kf = *reinterpret_cast<const bf16x8*>(
            (const char*)Ks + ((row * 256 + s * 32 + h * 16) ^ swz));
        sa[ni] = MFMA32(kf, qf[s], sa[ni]);
      }
    }
    __builtin_amdgcn_s_setprio(0);

    if (j >= 2 * qb) {
#pragma unroll
      for (int ni = 0; ni < 2; ++ni) {
        const int kvb = j * 64 + ni * 32 + 4 * h;
#pragma unroll
        for (int r = 0; r < 16; ++r) {
          int kvg = kvb + (r & 3) + 8 * (r >> 2);
          if (kvg > qg) sa[ni][r] = -__builtin_inff();
        }
      }
    }

    float pmax = sa[0][0];
#pragma unroll
    for (int r = 1; r < 16; ++r) pmax = fmaxf(pmax, sa[0][r]);
#pragma unroll
    for (int r = 0; r < 16; ++r) pmax = fmaxf(pmax, sa[1][r]);
    pmax = fmaxf(pmax, __shfl_xor(pmax, 32));

    if (!__all(pmax <= mrow + 8.0f)) {
      float mnew = fmaxf(mrow, pmax);
      float sf = __expf(mrow - mnew);
#pragma unroll
      for (int d = 0; d < 4; ++d)
#pragma unroll
        for (int r = 0; r < 16; ++r) po[d][r] *= sf;
      lrow *= sf;
      mrow = mnew;
    }

    float rs = 0.f;
#pragma unroll
    for (int ni = 0; ni < 2; ++ni)
#pragma unroll
      for (int r = 0; r < 16; ++r) {
        float p = __expf(sa[ni][r] - mrow);
        sa[ni][r] = p;
        rs += p;
      }
    rs += __shfl_xor(rs, 32);
    lrow += rs;

    bf16x8 pfrag[4];
#pragma unroll
    for (int ni = 0; ni < 2; ++ni) {
      unsigned wd[8];
#pragma unroll
      for (int c = 0; c < 4; ++c)
#pragma unroll
        for (int ii = 0; ii < 2; ++ii)
          wd[c * 2 + ii] = (unsigned)f2b(sa[ni][4 * c + 2 * ii]) |
                           ((unsigned)f2b(sa[ni][4 * c + 2 * ii + 1]) << 16);
#pragma unroll
      for (int k2 = 0; k2 < 2; ++k2) {
        unsigned e0 = wd[(2 * k2) * 2 + 0], e1 = wd[(2 * k2) * 2 + 1];
        unsigned o0 = wd[(2 * k2 + 1) * 2 + 0], o1 = wd[(2 * k2 + 1) * 2 + 1];
        unsigned pe0 = (unsigned)__shfl_xor((int)e0, 32);
        unsigned pe1 = (unsigned)__shfl_xor((int)e1, 32);
        unsigned po0 = (unsigned)__shfl_xor((int)o0, 32);
        unsigned po1 = (unsigned)__shfl_xor((int)o1, 32);
        union { unsigned u[4]; bf16x8 v; } uu;
        uu.u[0] = h ? po0 : e0;
        uu.u[1] = h ? po1 : e1;
        uu.u[2] = h ? o0 : pe0;
        uu.u[3] = h ? o1 : pe1;
        pfrag[ni * 2 + k2] = uu.v;
      }
    }

    __builtin_amdgcn_s_setprio(1);
#pragma unroll
    for (int d = 0; d < 4; ++d) {
      const int row0 = d * 32 + i5;
      const int swz = (row0 & 7) << 4;
#pragma unroll
      for (int ks = 0; ks < 4; ++ks) {
        bf16x8 vf = *reinterpret_cast<const bf16x8*>(
            (const char*)Vs + ((row0 * 128 + ks * 32 + h * 16) ^ swz));
        po[d] = MFMA32(vf, pfrag[ks], po[d]);
      }
    }
    __builtin_amdgcn_s_setprio(0);
  }

  const float inv = 1.0f / lrow;
#pragma unroll
  for (int d = 0; d < 4; ++d)
#pragma unroll
    for (int c = 0; c < 4; ++c) {
      ushort4 st;
      st.x = f2b(po[d][4 * c + 0] * inv);
      st.y = f2b(po[d][4 * c + 1] * inv);
      st.z = f2b(po[d][4 * c + 2] * inv);
      st.w = f2b(po[d][4 * c + 3] * inv);
      *reinterpret_cast<ushort4*>(
          ctx + (size_t)qg * 4096 + hd * 128 + d * 32 + 8 * c + 4 * h) = st;
    }
}

// ---------- launch ----------
extern "C" void kernel_launch(void* const* d_in, const int* in_sizes, int n_in,
                              void* d_out, int out_size, void* d_ws, size_t ws_size,
                              hipStream_t stream) {
  const float* X    = (const float*)d_in[0];
  const float* cosb = (const float*)d_in[2];
  const float* sinb = (const float*)d_in[3];
  const float* Wq   = (const float*)d_in[4];
  const float* Wk   = (const float*)d_in[5];
  const float* Wv   = (const float*)d_in[6];
  const float* Wo   = (const float*)d_in[7];

  char* ws = (char*)d_ws;
  unsigned short* WT   = (unsigned short*)(ws + 0);           // 6144x4096 bf16 (later: WoT)
  unsigned short* Xb   = (unsigned short*)(ws + 50331648ull); // 2048x4096 bf16
  unsigned short* Cpre = (unsigned short*)(ws + 67108864ull); // 2048x6144 bf16 (later: ctx)
  unsigned short* Qr   = (unsigned short*)(ws + 92274688ull); // 32x2048x128 bf16
  unsigned short* Kr   = (unsigned short*)(ws + 109051904ull);// 8x2048x128 bf16
  unsigned short* Vt   = (unsigned short*)(ws + 113246208ull);// 8x128x2048 bf16
  unsigned short* ctx  = Cpre;

  k_transpose_f32_bf16<<<dim3(64, 64), 256, 0, stream>>>(Wq, WT, 4096, 4096);
  k_transpose_f32_bf16<<<dim3(64, 16), 256, 0, stream>>>(Wk, WT + (size_t)4096 * 4096, 4096, 1024);
  k_transpose_f32_bf16<<<dim3(64, 16), 256, 0, stream>>>(Wv, WT + (size_t)5120 * 4096, 4096, 1024);
  k_f32_to_bf16<<<8192, 256, 0, stream>>>(X, Xb);

  // fused QKV projection: (2048x4096)@(4096x6144), 128^2 tiles, XCD-swizzled 1D grid (768)
  k_gemm<false><<<768, 256, 0, stream>>>(Xb, WT, Cpre, 2048, 6144, 4096);

  k_rope<<<dim3(2048, 20), 256, 0, stream>>>(Cpre, cosb, sinb, Qr, Kr);
  k_transpose_v<<<dim3(32, 2, 8), 256, 0, stream>>>(Cpre, Vt);

  k_transpose_f32_bf16<<<dim3(64, 64), 256, 0, stream>>>(Wo, WT, 4096, 4096);

  k_attn<<<512, 256, 0, stream>>>(Qr, Kr, Vt, ctx);

  // out projection: (2048x4096)@(4096x4096), XCD-swizzled 1D grid (512)
  k_gemm<true><<<512, 256, 0, stream>>>(ctx, WT, d_out, 2048, 4096, 4096);
}

// Round 10
// 349.026 us; speedup vs baseline: 1.5665x; 1.0237x over previous
//
#include <hip/hip_runtime.h>
#include <hip/hip_bf16.h>
#include <stdint.h>
#include <stddef.h>

// ---------- types ----------
typedef __attribute__((ext_vector_type(8))) short bf16x8;          // 8 bf16 in 4 VGPRs
typedef __attribute__((ext_vector_type(8))) unsigned short u16x8;  // 16B vector
typedef __attribute__((ext_vector_type(4))) float f32x4;
typedef __attribute__((ext_vector_type(16))) float f32x16;

#define MFMA16(a, b, c) __builtin_amdgcn_mfma_f32_16x16x32_bf16((a), (b), (c), 0, 0, 0)
#define MFMA32(a, b, c) __builtin_amdgcn_mfma_f32_32x32x16_bf16((a), (b), (c), 0, 0, 0)

__device__ __forceinline__ unsigned short f2b(float f) {  // f32 -> bf16 RNE
  union { float f; unsigned u; } v; v.f = f;
  unsigned r = v.u + 0x7fffu + ((v.u >> 16) & 1u);
  return (unsigned short)(r >> 16);
}
__device__ __forceinline__ float b2f(unsigned short h) {
  union { unsigned u; float f; } v; v.u = ((unsigned)h) << 16;
  return v.f;
}

__device__ __forceinline__ void gload_lds16(const void* g, void* l) {
  __builtin_amdgcn_global_load_lds((const __attribute__((address_space(1))) void*)g,
                                   (__attribute__((address_space(3))) void*)l, 16, 0, 0);
}

// ---------- fused Wq/Wk/Wv transpose+convert -> WT[n][k] (n<6144, k<4096) ----------
__global__ void k_transpose_qkv(const float* __restrict__ Wq, const float* __restrict__ Wk,
                                const float* __restrict__ Wv, unsigned short* __restrict__ out) {
  __shared__ float tile[64][65];
  const int kb = blockIdx.x * 64;
  const int nbg = blockIdx.y * 64;          // fused output row block (0..6143)
  const float* src; int srcN, nb;
  if (nbg < 4096)      { src = Wq; srcN = 4096; nb = nbg; }
  else if (nbg < 5120) { src = Wk; srcN = 1024; nb = nbg - 4096; }
  else                 { src = Wv; srcN = 1024; nb = nbg - 5120; }
  const int t = threadIdx.x;
  const int c4 = (t & 15) * 4;
  const int rr = t >> 4;
#pragma unroll
  for (int i = 0; i < 4; ++i) {
    int r = rr + i * 16;
    float4 v = *reinterpret_cast<const float4*>(src + (size_t)(kb + r) * srcN + nb + c4);
    tile[r][c4 + 0] = v.x; tile[r][c4 + 1] = v.y;
    tile[r][c4 + 2] = v.z; tile[r][c4 + 3] = v.w;
  }
  __syncthreads();
#pragma unroll
  for (int i = 0; i < 4; ++i) {
    int n = rr + i * 16;
    ushort4 w;
    w.x = f2b(tile[c4 + 0][n]); w.y = f2b(tile[c4 + 1][n]);
    w.z = f2b(tile[c4 + 2][n]); w.w = f2b(tile[c4 + 3][n]);
    *reinterpret_cast<ushort4*>(out + (size_t)(nbg + n) * 4096 + kb + c4) = w;
  }
}

// ---------- transpose + convert f32 (K x N) -> bf16 (N x K) ----------
__global__ void k_transpose_f32_bf16(const float* __restrict__ in,
                                     unsigned short* __restrict__ out,
                                     int K, int N) {
  __shared__ float tile[64][65];
  const int kb = blockIdx.x * 64;
  const int nb = blockIdx.y * 64;
  const int t = threadIdx.x;
  const int c4 = (t & 15) * 4;
  const int rr = t >> 4;
#pragma unroll
  for (int i = 0; i < 4; ++i) {
    int r = rr + i * 16;
    float4 v = *reinterpret_cast<const float4*>(in + (size_t)(kb + r) * N + nb + c4);
    tile[r][c4 + 0] = v.x; tile[r][c4 + 1] = v.y;
    tile[r][c4 + 2] = v.z; tile[r][c4 + 3] = v.w;
  }
  __syncthreads();
#pragma unroll
  for (int i = 0; i < 4; ++i) {
    int n = rr + i * 16;
    ushort4 w;
    w.x = f2b(tile[c4 + 0][n]); w.y = f2b(tile[c4 + 1][n]);
    w.z = f2b(tile[c4 + 2][n]); w.w = f2b(tile[c4 + 3][n]);
    *reinterpret_cast<ushort4*>(out + (size_t)(nb + n) * K + kb + c4) = w;
  }
}

// ---------- elementwise f32 -> bf16 ----------
__global__ void k_f32_to_bf16(const float* __restrict__ in, unsigned short* __restrict__ out) {
  size_t i = ((size_t)blockIdx.x * blockDim.x + threadIdx.x) * 4;
  float4 v = *reinterpret_cast<const float4*>(in + i);
  ushort4 w; w.x = f2b(v.x); w.y = f2b(v.y); w.z = f2b(v.z); w.w = f2b(v.w);
  *reinterpret_cast<ushort4*>(out + i) = w;
}

// ---------- GEMM (m97 + T1 XCD swizzle): C[M,N] = A[M,K] * Bt[N,K]^T ----------
template <bool OUT_F32>
__global__ void __launch_bounds__(256, 2)
k_gemm(const unsigned short* __restrict__ A, const unsigned short* __restrict__ Bt,
       void* __restrict__ C, int M, int N, int K) {
  __shared__ unsigned short As[128 * 32];
  __shared__ unsigned short Bs[128 * 32];
  const int nbm = M >> 7;
  const int per = ((M >> 7) * (N >> 7)) >> 3;
  const int wg  = (blockIdx.x & 7) * per + (blockIdx.x >> 3);
  const int m0 = (wg % nbm) * 128;
  const int n0 = (wg / nbm) * 128;
  const int tid = threadIdx.x;
  const int lane = tid & 63;
  const int w = tid >> 6;
  const int wr = w >> 1, wc = w & 1;
  const int cl = lane & 15, rg = lane >> 4;
  const int ko = rg * 8;

  f32x4 acc[4][4] = {};

  for (int k0 = 0; k0 < K; k0 += 32) {
#pragma unroll
    for (int i = 0; i < 2; ++i) {
      int c = i * 256 + tid;
      gload_lds16(A + (size_t)(m0 + (c >> 2)) * K + k0 + (c & 3) * 8, As + c * 8);
    }
#pragma unroll
    for (int i = 0; i < 2; ++i) {
      int c = i * 256 + tid;
      gload_lds16(Bt + (size_t)(n0 + (c >> 2)) * K + k0 + (c & 3) * 8, Bs + c * 8);
    }
    __syncthreads();
    bf16x8 a[4], b[4];
#pragma unroll
    for (int mi = 0; mi < 4; ++mi)
      a[mi] = *reinterpret_cast<const bf16x8*>(As + (wr * 64 + mi * 16 + cl) * 32 + ko);
#pragma unroll
    for (int ni = 0; ni < 4; ++ni)
      b[ni] = *reinterpret_cast<const bf16x8*>(Bs + (wc * 64 + ni * 16 + cl) * 32 + ko);
#pragma unroll
    for (int mi = 0; mi < 4; ++mi)
#pragma unroll
      for (int ni = 0; ni < 4; ++ni)
        acc[mi][ni] = MFMA16(a[mi], b[ni], acc[mi][ni]);
    __syncthreads();
  }
#pragma unroll
  for (int mi = 0; mi < 4; ++mi)
#pragma unroll
    for (int ni = 0; ni < 4; ++ni) {
      int row = m0 + wr * 64 + mi * 16 + rg * 4;
      int col = n0 + wc * 64 + ni * 16 + cl;
#pragma unroll
      for (int r = 0; r < 4; ++r) {
        float v = acc[mi][ni][r];
        if (OUT_F32) ((float*)C)[(size_t)(row + r) * N + col] = v;
        else         ((unsigned short*)C)[(size_t)(row + r) * N + col] = f2b(v);
      }
    }
}

// ---------- RoPE + reshape ----------
__global__ void k_rope(const unsigned short* __restrict__ Cpre,
                       const float* __restrict__ cosb, const float* __restrict__ sinb,
                       unsigned short* __restrict__ Qr, unsigned short* __restrict__ Kr) {
  const int s = blockIdx.x;
  const int hh = blockIdx.y * 2 + (threadIdx.x >> 7);
  const int d = threadIdx.x & 127;
  const int col = (hh < 32) ? hh * 128 + d : 4096 + (hh - 32) * 128 + d;
  float t = b2f(Cpre[(size_t)s * 6144 + col]);
  const int dp = (d < 64) ? d + 64 : d - 64;
  float tp = b2f(Cpre[(size_t)s * 6144 + (col - d + dp)]);
  float rot = (d < 64) ? -tp : tp;
  float o = t * cosb[s * 128 + d] + rot * sinb[s * 128 + d];
  if (hh < 32) {
    Qr[((size_t)hh * 2048 + s) * 128 + d] = f2b(o * 0.08838834764831845f);
  } else {
    Kr[((size_t)(hh - 32) * 2048 + s) * 128 + d] = f2b(o);
  }
}

// ---------- V transpose: Cpre[S, 5120 + kv*128 + d] -> Vt[KV, DH, S] ----------
__global__ void k_transpose_v(const unsigned short* __restrict__ Cpre,
                              unsigned short* __restrict__ Vt) {
  __shared__ unsigned short tile[64][72];
  const int sb = blockIdx.x * 64;
  const int db = blockIdx.y * 64;
  const int kv = blockIdx.z;
  const int t = threadIdx.x;
#pragma unroll
  for (int i = 0; i < 2; ++i) {
    int sl = i * 32 + (t >> 3);
    int d8 = (t & 7) * 8;
    const unsigned short* src = Cpre + (size_t)(sb + sl) * 6144 + 5120 + kv * 128 + db + d8;
    ushort4 v0 = *reinterpret_cast<const ushort4*>(src);
    ushort4 v1 = *reinterpret_cast<const ushort4*>(src + 4);
    *reinterpret_cast<ushort4*>(&tile[sl][d8]) = v0;
    *reinterpret_cast<ushort4*>(&tile[sl][d8 + 4]) = v1;
  }
  __syncthreads();
#pragma unroll
  for (int i = 0; i < 2; ++i) {
    int dl = i * 32 + (t >> 3);
    int s8 = (t & 7) * 8;
    ushort4 w0, w1;
    w0.x = tile[s8 + 0][dl]; w0.y = tile[s8 + 1][dl]; w0.z = tile[s8 + 2][dl]; w0.w = tile[s8 + 3][dl];
    w1.x = tile[s8 + 4][dl]; w1.y = tile[s8 + 5][dl]; w1.z = tile[s8 + 6][dl]; w1.w = tile[s8 + 7][dl];
    unsigned short* dst = Vt + ((size_t)kv * 128 + db + dl) * 2048 + sb + s8;
    *reinterpret_cast<ushort4*>(dst) = w0;
    *reinterpret_cast<ushort4*>(dst + 4) = w1;
  }
}

// ---------- fused causal GQA flash attention (v7) ----------
// R7 compute (swapped-QK 32x32, in-reg softmax) + gload_lds-direct double-buffered
// K/V staging with ONE counted vmcnt(8) gate per iter (minimal T3/T4 form).
// Linear LDS dest + pre-swizzled global source + swizzled reads (rule #21).
__global__ void __launch_bounds__(256, 2)
k_attn(const unsigned short* __restrict__ Qr, const unsigned short* __restrict__ Kr,
       const unsigned short* __restrict__ Vt, unsigned short* __restrict__ ctx) {
  __shared__ unsigned short Ks[2][64 * 128];   // [buf][kv][d] swizzled, 16KB each
  __shared__ unsigned short Vs[2][128 * 64];   // [buf][d][kv] swizzled, 16KB each
  const int bid = blockIdx.x;
  const int kv = bid & 7;                   // XCD-aligned kv head
  const int hd = kv * 4 + ((bid >> 3) & 3);
  const int qb = 15 - (bid >> 5);           // heavy-first
  const int q0 = qb * 128;
  const int tid = threadIdx.x;
  const int l = tid & 63;
  const int w = tid >> 6;
  const int i5 = l & 31;                    // q-col index within wave
  const int h  = l >> 5;                    // lane half
  const int qg = q0 + w * 16 + (i5 & 15) + (i5 >> 4) * 64;

  const char* Kbase = (const char*)(Kr + (size_t)kv * 2048 * 128);
  const char* Vbase = (const char*)(Vt + (size_t)kv * 128 * 2048);

  // Q B-fragments (pre-scaled by 1/sqrt(d))
  bf16x8 qf[8];
#pragma unroll
  for (int s = 0; s < 8; ++s)
    qf[s] = *reinterpret_cast<const bf16x8*>(
        Qr + ((size_t)hd * 2048 + qg) * 128 + s * 16 + h * 8);

  f32x16 po[4] = {};
  float mrow = -1e30f, lrow = 0.f;

  // staging geometry: 8 gload_lds per thread per tile; dest linear, src pre-swizzled
  const int krow = tid >> 4;            // 0..15
  const int kcol = (tid & 15) * 16;     // byte col in 256B K row
  const int vrow = tid >> 3;            // 0..31
  const int vcol = (tid & 7) * 16;      // byte col in 128B V row

#define STAGE_KV(JT, BUF)                                                      \
  {                                                                            \
    _Pragma("unroll")                                                          \
    for (int ii = 0; ii < 4; ++ii) {                                           \
      int row = ii * 16 + krow;                                                \
      gload_lds16(Kbase + (size_t)((JT) * 64 + row) * 256 +                    \
                      (kcol ^ ((row & 7) << 4)),                               \
                  (char*)Ks[BUF] + row * 256 + kcol);                          \
    }                                                                          \
    _Pragma("unroll")                                                          \
    for (int ii = 0; ii < 4; ++ii) {                                           \
      int row = ii * 32 + vrow;                                                \
      gload_lds16(Vbase + (size_t)row * 4096 + (JT) * 128 +                    \
                      (vcol ^ ((row & 7) << 4)),                               \
                  (char*)Vs[BUF] + row * 128 + vcol);                          \
    }                                                                          \
  }

  // prologue: tile 0 -> buf 0 (8 loads in flight)
  STAGE_KV(0, 0)

  const int jmax = 2 * qb + 2;
  for (int j = 0; j < jmax; ++j) {
    const int cur = j & 1;
    const int jn = (j + 1 < jmax) ? j + 1 : j;   // clamp keeps vmcnt count uniform
    // issue next tile into the other buffer (stays in flight across compute)
    STAGE_KV(jn, cur ^ 1)
    // gate: tile j (8 oldest) landed; 8 newest stay in flight
    asm volatile("s_waitcnt vmcnt(8)" ::: "memory");
    __builtin_amdgcn_sched_barrier(0);
    __builtin_amdgcn_s_barrier();
    __builtin_amdgcn_sched_barrier(0);

    const unsigned short* Kc = Ks[cur];
    const unsigned short* Vc = Vs[cur];

    // S^T[kv][q] = mfma32(A=K rows, B=Q)
    f32x16 sa[2] = {};
    __builtin_amdgcn_s_setprio(1);
#pragma unroll
    for (int ni = 0; ni < 2; ++ni) {
      const int row = ni * 32 + i5;
      const int swz = (row & 7) << 4;
#pragma unroll
      for (int s = 0; s < 8; ++s) {
        bf16x8 kf = *reinterpret_cast<const bf16x8*>(
            (const char*)Kc + ((row * 256 + s * 32 + h * 16) ^ swz));
        sa[ni] = MFMA32(kf, qf[s], sa[ni]);
      }
    }
    __builtin_amdgcn_s_setprio(0);

    // causal mask (diagonal region only)
    if (j >= 2 * qb) {
#pragma unroll
      for (int ni = 0; ni < 2; ++ni) {
        const int kvb = j * 64 + ni * 32 + 4 * h;
#pragma unroll
        for (int r = 0; r < 16; ++r) {
          int kvg = kvb + (r & 3) + 8 * (r >> 2);
          if (kvg > qg) sa[ni][r] = -__builtin_inff();
        }
      }
    }

    // in-lane row max + 1 cross-half shfl
    float pmax = sa[0][0];
#pragma unroll
    for (int r = 1; r < 16; ++r) pmax = fmaxf(pmax, sa[0][r]);
#pragma unroll
    for (int r = 0; r < 16; ++r) pmax = fmaxf(pmax, sa[1][r]);
    pmax = fmaxf(pmax, __shfl_xor(pmax, 32));

    // defer-max rescale (T13, THR=8)
    if (!__all(pmax <= mrow + 8.0f)) {
      float mnew = fmaxf(mrow, pmax);
      float sf = __expf(mrow - mnew);
#pragma unroll
      for (int d = 0; d < 4; ++d)
#pragma unroll
        for (int r = 0; r < 16; ++r) po[d][r] *= sf;
      lrow *= sf;
      mrow = mnew;
    }

    // exp + in-lane sum + 1 shfl
    float rs = 0.f;
#pragma unroll
    for (int ni = 0; ni < 2; ++ni)
#pragma unroll
      for (int r = 0; r < 16; ++r) {
        float p = __expf(sa[ni][r] - mrow);
        sa[ni][r] = p;
        rs += p;
      }
    rs += __shfl_xor(rs, 32);
    lrow += rs;

    // pack P -> PV B-fragments via shfl_xor(32) word exchange
    bf16x8 pfrag[4];
#pragma unroll
    for (int ni = 0; ni < 2; ++ni) {
      unsigned wd[8];
#pragma unroll
      for (int c = 0; c < 4; ++c)
#pragma unroll
        for (int ii = 0; ii < 2; ++ii)
          wd[c * 2 + ii] = (unsigned)f2b(sa[ni][4 * c + 2 * ii]) |
                           ((unsigned)f2b(sa[ni][4 * c + 2 * ii + 1]) << 16);
#pragma unroll
      for (int k2 = 0; k2 < 2; ++k2) {
        unsigned e0 = wd[(2 * k2) * 2 + 0], e1 = wd[(2 * k2) * 2 + 1];
        unsigned o0 = wd[(2 * k2 + 1) * 2 + 0], o1 = wd[(2 * k2 + 1) * 2 + 1];
        unsigned pe0 = (unsigned)__shfl_xor((int)e0, 32);
        unsigned pe1 = (unsigned)__shfl_xor((int)e1, 32);
        unsigned po0 = (unsigned)__shfl_xor((int)o0, 32);
        unsigned po1 = (unsigned)__shfl_xor((int)o1, 32);
        union { unsigned u[4]; bf16x8 v; } uu;
        uu.u[0] = h ? po0 : e0;
        uu.u[1] = h ? po1 : e1;
        uu.u[2] = h ? o0 : pe0;
        uu.u[3] = h ? o1 : pe1;
        pfrag[ni * 2 + k2] = uu.v;
      }
    }

    // O^T += V^T P^T
    __builtin_amdgcn_s_setprio(1);
#pragma unroll
    for (int d = 0; d < 4; ++d) {
      const int row0 = d * 32 + i5;
      const int swz = (row0 & 7) << 4;
#pragma unroll
      for (int ks = 0; ks < 4; ++ks) {
        bf16x8 vf = *reinterpret_cast<const bf16x8*>(
            (const char*)Vc + ((row0 * 128 + ks * 32 + h * 16) ^ swz));
        po[d] = MFMA32(vf, pfrag[ks], po[d]);
      }
    }
    __builtin_amdgcn_s_setprio(0);

    // end barrier: all waves done reading buf cur before next iter overwrites it
    __builtin_amdgcn_sched_barrier(0);
    __builtin_amdgcn_s_barrier();
    __builtin_amdgcn_sched_barrier(0);
  }
#undef STAGE_KV

  // epilogue: normalize, write ctx[q][hd*128+d]
  const float inv = 1.0f / lrow;
#pragma unroll
  for (int d = 0; d < 4; ++d)
#pragma unroll
    for (int c = 0; c < 4; ++c) {
      ushort4 st;
      st.x = f2b(po[d][4 * c + 0] * inv);
      st.y = f2b(po[d][4 * c + 1] * inv);
      st.z = f2b(po[d][4 * c + 2] * inv);
      st.w = f2b(po[d][4 * c + 3] * inv);
      *reinterpret_cast<ushort4*>(
          ctx + (size_t)qg * 4096 + hd * 128 + d * 32 + 8 * c + 4 * h) = st;
    }
}

// ---------- launch ----------
extern "C" void kernel_launch(void* const* d_in, const int* in_sizes, int n_in,
                              void* d_out, int out_size, void* d_ws, size_t ws_size,
                              hipStream_t stream) {
  const float* X    = (const float*)d_in[0];
  const float* cosb = (const float*)d_in[2];
  const float* sinb = (const float*)d_in[3];
  const float* Wq   = (const float*)d_in[4];
  const float* Wk   = (const float*)d_in[5];
  const float* Wv   = (const float*)d_in[6];
  const float* Wo   = (const float*)d_in[7];

  char* ws = (char*)d_ws;
  unsigned short* WT   = (unsigned short*)(ws + 0);           // 6144x4096 bf16 (later: WoT)
  unsigned short* Xb   = (unsigned short*)(ws + 50331648ull); // 2048x4096 bf16
  unsigned short* Cpre = (unsigned short*)(ws + 67108864ull); // 2048x6144 bf16 (later: ctx)
  unsigned short* Qr   = (unsigned short*)(ws + 92274688ull); // 32x2048x128 bf16
  unsigned short* Kr   = (unsigned short*)(ws + 109051904ull);// 8x2048x128 bf16
  unsigned short* Vt   = (unsigned short*)(ws + 113246208ull);// 8x128x2048 bf16
  unsigned short* ctx  = Cpre;

  // fused Wq/Wk/Wv transpose -> WT (one launch), X -> bf16
  k_transpose_qkv<<<dim3(64, 96), 256, 0, stream>>>(Wq, Wk, Wv, WT);
  k_f32_to_bf16<<<8192, 256, 0, stream>>>(X, Xb);

  // fused QKV projection: 128^2 tiles, XCD-swizzled 1D grid (768)
  k_gemm<false><<<768, 256, 0, stream>>>(Xb, WT, Cpre, 2048, 6144, 4096);

  k_rope<<<dim3(2048, 20), 256, 0, stream>>>(Cpre, cosb, sinb, Qr, Kr);
  k_transpose_v<<<dim3(32, 2, 8), 256, 0, stream>>>(Cpre, Vt);

  k_transpose_f32_bf16<<<dim3(64, 64), 256, 0, stream>>>(Wo, WT, 4096, 4096);

  k_attn<<<512, 256, 0, stream>>>(Qr, Kr, Vt, ctx);

  // out projection: XCD-swizzled 1D grid (512)
  k_gemm<true><<<512, 256, 0, stream>>>(ctx, WT, d_out, 2048, 4096, 4096);
}

// Round 11
// 323.468 us; speedup vs baseline: 1.6903x; 1.0790x over previous
//
#include <hip/hip_runtime.h>
#include <hip/hip_bf16.h>
#include <stdint.h>
#include <stddef.h>

// ---------- types ----------
typedef __attribute__((ext_vector_type(8))) short bf16x8;          // 8 bf16 in 4 VGPRs
typedef __attribute__((ext_vector_type(8))) unsigned short u16x8;  // 16B vector
typedef __attribute__((ext_vector_type(4))) float f32x4;
typedef __attribute__((ext_vector_type(16))) float f32x16;

#define MFMA16(a, b, c) __builtin_amdgcn_mfma_f32_16x16x32_bf16((a), (b), (c), 0, 0, 0)
#define MFMA32(a, b, c) __builtin_amdgcn_mfma_f32_32x32x16_bf16((a), (b), (c), 0, 0, 0)

__device__ __forceinline__ unsigned short f2b(float f) {  // f32 -> bf16 RNE
  union { float f; unsigned u; } v; v.f = f;
  unsigned r = v.u + 0x7fffu + ((v.u >> 16) & 1u);
  return (unsigned short)(r >> 16);
}
__device__ __forceinline__ float b2f(unsigned short h) {
  union { unsigned u; float f; } v; v.u = ((unsigned)h) << 16;
  return v.f;
}

__device__ __forceinline__ void gload_lds16(const void* g, void* l) {
  __builtin_amdgcn_global_load_lds((const __attribute__((address_space(1))) void*)g,
                                   (__attribute__((address_space(3))) void*)l, 16, 0, 0);
}

// ---------- fused Wq/Wk/Wv transpose+convert -> WT[n][k] (n<6144, k<4096) ----------
__global__ void k_transpose_qkv(const float* __restrict__ Wq, const float* __restrict__ Wk,
                                const float* __restrict__ Wv, unsigned short* __restrict__ out) {
  __shared__ float tile[64][65];
  const int kb = blockIdx.x * 64;
  const int nbg = blockIdx.y * 64;          // fused output row block (0..6143)
  const float* src; int srcN, nb;
  if (nbg < 4096)      { src = Wq; srcN = 4096; nb = nbg; }
  else if (nbg < 5120) { src = Wk; srcN = 1024; nb = nbg - 4096; }
  else                 { src = Wv; srcN = 1024; nb = nbg - 5120; }
  const int t = threadIdx.x;
  const int c4 = (t & 15) * 4;
  const int rr = t >> 4;
#pragma unroll
  for (int i = 0; i < 4; ++i) {
    int r = rr + i * 16;
    float4 v = *reinterpret_cast<const float4*>(src + (size_t)(kb + r) * srcN + nb + c4);
    tile[r][c4 + 0] = v.x; tile[r][c4 + 1] = v.y;
    tile[r][c4 + 2] = v.z; tile[r][c4 + 3] = v.w;
  }
  __syncthreads();
#pragma unroll
  for (int i = 0; i < 4; ++i) {
    int n = rr + i * 16;
    ushort4 w;
    w.x = f2b(tile[c4 + 0][n]); w.y = f2b(tile[c4 + 1][n]);
    w.z = f2b(tile[c4 + 2][n]); w.w = f2b(tile[c4 + 3][n]);
    *reinterpret_cast<ushort4*>(out + (size_t)(nbg + n) * 4096 + kb + c4) = w;
  }
}

// ---------- transpose + convert f32 (K x N) -> bf16 (N x K) ----------
__global__ void k_transpose_f32_bf16(const float* __restrict__ in,
                                     unsigned short* __restrict__ out,
                                     int K, int N) {
  __shared__ float tile[64][65];
  const int kb = blockIdx.x * 64;
  const int nb = blockIdx.y * 64;
  const int t = threadIdx.x;
  const int c4 = (t & 15) * 4;
  const int rr = t >> 4;
#pragma unroll
  for (int i = 0; i < 4; ++i) {
    int r = rr + i * 16;
    float4 v = *reinterpret_cast<const float4*>(in + (size_t)(kb + r) * N + nb + c4);
    tile[r][c4 + 0] = v.x; tile[r][c4 + 1] = v.y;
    tile[r][c4 + 2] = v.z; tile[r][c4 + 3] = v.w;
  }
  __syncthreads();
#pragma unroll
  for (int i = 0; i < 4; ++i) {
    int n = rr + i * 16;
    ushort4 w;
    w.x = f2b(tile[c4 + 0][n]); w.y = f2b(tile[c4 + 1][n]);
    w.z = f2b(tile[c4 + 2][n]); w.w = f2b(tile[c4 + 3][n]);
    *reinterpret_cast<ushort4*>(out + (size_t)(nb + n) * K + kb + c4) = w;
  }
}

// ---------- elementwise f32 -> bf16 ----------
__global__ void k_f32_to_bf16(const float* __restrict__ in, unsigned short* __restrict__ out) {
  size_t i = ((size_t)blockIdx.x * blockDim.x + threadIdx.x) * 4;
  float4 v = *reinterpret_cast<const float4*>(in + i);
  ushort4 w; w.x = f2b(v.x); w.y = f2b(v.y); w.z = f2b(v.z); w.w = f2b(v.w);
  *reinterpret_cast<ushort4*>(out + i) = w;
}

// ---------- GEMM (m97 structure, BK=64 + swizzled staging + T1 XCD swizzle) ----------
// BK 32->64 halves the barrier count (the documented ~20% drain stall).
// 128B LDS row stride would be a 32-way conflict; fixed via rule-#21 involution:
// pre-swizzled gload source col ^ ((row&7)<<4), same XOR on fragment reads.
template <bool OUT_F32>
__global__ void __launch_bounds__(256, 2)
k_gemm(const unsigned short* __restrict__ A, const unsigned short* __restrict__ Bt,
       void* __restrict__ C, int M, int N, int K) {
  __shared__ unsigned short As[128 * 64];
  __shared__ unsigned short Bs[128 * 64];
  const int nbm = M >> 7;
  const int per = ((M >> 7) * (N >> 7)) >> 3;
  const int wg  = (blockIdx.x & 7) * per + (blockIdx.x >> 3);
  const int m0 = (wg % nbm) * 128;
  const int n0 = (wg / nbm) * 128;
  const int tid = threadIdx.x;
  const int lane = tid & 63;
  const int w = tid >> 6;
  const int wr = w >> 1, wc = w & 1;
  const int cl = lane & 15, rg = lane >> 4;

  f32x4 acc[4][4] = {};

  for (int k0 = 0; k0 < K; k0 += 64) {
    // stage 128x64 A and B: 4 gloads each per thread; src col pre-swizzled
#pragma unroll
    for (int i = 0; i < 4; ++i) {
      int c = i * 256 + tid;          // 0..1023
      int row = c >> 3;
      int sc = ((c & 7) * 8) ^ ((row & 7) * 8);   // elems; ^(row&7)<<4 bytes
      gload_lds16(A + (size_t)(m0 + row) * K + k0 + sc, As + c * 8);
    }
#pragma unroll
    for (int i = 0; i < 4; ++i) {
      int c = i * 256 + tid;
      int row = c >> 3;
      int sc = ((c & 7) * 8) ^ ((row & 7) * 8);
      gload_lds16(Bt + (size_t)(n0 + row) * K + k0 + sc, Bs + c * 8);
    }
    __syncthreads();
    bf16x8 a[4][2], b[4][2];
#pragma unroll
    for (int mi = 0; mi < 4; ++mi) {
      int row = wr * 64 + mi * 16 + cl;
      int swz = (row & 7) << 4;   // byte XOR
#pragma unroll
      for (int ks = 0; ks < 2; ++ks)
        a[mi][ks] = *reinterpret_cast<const bf16x8*>(
            (const char*)As + ((row * 128 + (ks * 32 + rg * 8) * 2) ^ swz));
    }
#pragma unroll
    for (int ni = 0; ni < 4; ++ni) {
      int row = wc * 64 + ni * 16 + cl;
      int swz = (row & 7) << 4;
#pragma unroll
      for (int ks = 0; ks < 2; ++ks)
        b[ni][ks] = *reinterpret_cast<const bf16x8*>(
            (const char*)Bs + ((row * 128 + (ks * 32 + rg * 8) * 2) ^ swz));
    }
#pragma unroll
    for (int ks = 0; ks < 2; ++ks)
#pragma unroll
      for (int mi = 0; mi < 4; ++mi)
#pragma unroll
        for (int ni = 0; ni < 4; ++ni)
          acc[mi][ni] = MFMA16(a[mi][ks], b[ni][ks], acc[mi][ni]);
    __syncthreads();
  }
#pragma unroll
  for (int mi = 0; mi < 4; ++mi)
#pragma unroll
    for (int ni = 0; ni < 4; ++ni) {
      int row = m0 + wr * 64 + mi * 16 + rg * 4;
      int col = n0 + wc * 64 + ni * 16 + cl;
#pragma unroll
      for (int r = 0; r < 4; ++r) {
        float v = acc[mi][ni][r];
        if (OUT_F32) ((float*)C)[(size_t)(row + r) * N + col] = v;
        else         ((unsigned short*)C)[(size_t)(row + r) * N + col] = f2b(v);
      }
    }
}

// ---------- RoPE + reshape ----------
__global__ void k_rope(const unsigned short* __restrict__ Cpre,
                       const float* __restrict__ cosb, const float* __restrict__ sinb,
                       unsigned short* __restrict__ Qr, unsigned short* __restrict__ Kr) {
  const int s = blockIdx.x;
  const int hh = blockIdx.y * 2 + (threadIdx.x >> 7);
  const int d = threadIdx.x & 127;
  const int col = (hh < 32) ? hh * 128 + d : 4096 + (hh - 32) * 128 + d;
  float t = b2f(Cpre[(size_t)s * 6144 + col]);
  const int dp = (d < 64) ? d + 64 : d - 64;
  float tp = b2f(Cpre[(size_t)s * 6144 + (col - d + dp)]);
  float rot = (d < 64) ? -tp : tp;
  float o = t * cosb[s * 128 + d] + rot * sinb[s * 128 + d];
  if (hh < 32) {
    Qr[((size_t)hh * 2048 + s) * 128 + d] = f2b(o * 0.08838834764831845f);
  } else {
    Kr[((size_t)(hh - 32) * 2048 + s) * 128 + d] = f2b(o);
  }
}

// ---------- V transpose: Cpre[S, 5120 + kv*128 + d] -> Vt[KV, DH, S] ----------
__global__ void k_transpose_v(const unsigned short* __restrict__ Cpre,
                              unsigned short* __restrict__ Vt) {
  __shared__ unsigned short tile[64][72];
  const int sb = blockIdx.x * 64;
  const int db = blockIdx.y * 64;
  const int kv = blockIdx.z;
  const int t = threadIdx.x;
#pragma unroll
  for (int i = 0; i < 2; ++i) {
    int sl = i * 32 + (t >> 3);
    int d8 = (t & 7) * 8;
    const unsigned short* src = Cpre + (size_t)(sb + sl) * 6144 + 5120 + kv * 128 + db + d8;
    ushort4 v0 = *reinterpret_cast<const ushort4*>(src);
    ushort4 v1 = *reinterpret_cast<const ushort4*>(src + 4);
    *reinterpret_cast<ushort4*>(&tile[sl][d8]) = v0;
    *reinterpret_cast<ushort4*>(&tile[sl][d8 + 4]) = v1;
  }
  __syncthreads();
#pragma unroll
  for (int i = 0; i < 2; ++i) {
    int dl = i * 32 + (t >> 3);
    int s8 = (t & 7) * 8;
    ushort4 w0, w1;
    w0.x = tile[s8 + 0][dl]; w0.y = tile[s8 + 1][dl]; w0.z = tile[s8 + 2][dl]; w0.w = tile[s8 + 3][dl];
    w1.x = tile[s8 + 4][dl]; w1.y = tile[s8 + 5][dl]; w1.z = tile[s8 + 6][dl]; w1.w = tile[s8 + 7][dl];
    unsigned short* dst = Vt + ((size_t)kv * 128 + db + dl) * 2048 + sb + s8;
    *reinterpret_cast<ushort4*>(dst) = w0;
    *reinterpret_cast<ushort4*>(dst + 4) = w1;
  }
}

// ---------- fused causal GQA flash attention (R10 known-good) ----------
__global__ void __launch_bounds__(256, 2)
k_attn(const unsigned short* __restrict__ Qr, const unsigned short* __restrict__ Kr,
       const unsigned short* __restrict__ Vt, unsigned short* __restrict__ ctx) {
  __shared__ unsigned short Ks[2][64 * 128];   // [buf][kv][d] swizzled, 16KB each
  __shared__ unsigned short Vs[2][128 * 64];   // [buf][d][kv] swizzled, 16KB each
  const int bid = blockIdx.x;
  const int kv = bid & 7;
  const int hd = kv * 4 + ((bid >> 3) & 3);
  const int qb = 15 - (bid >> 5);
  const int q0 = qb * 128;
  const int tid = threadIdx.x;
  const int l = tid & 63;
  const int w = tid >> 6;
  const int i5 = l & 31;
  const int h  = l >> 5;
  const int qg = q0 + w * 16 + (i5 & 15) + (i5 >> 4) * 64;

  const char* Kbase = (const char*)(Kr + (size_t)kv * 2048 * 128);
  const char* Vbase = (const char*)(Vt + (size_t)kv * 128 * 2048);

  bf16x8 qf[8];
#pragma unroll
  for (int s = 0; s < 8; ++s)
    qf[s] = *reinterpret_cast<const bf16x8*>(
        Qr + ((size_t)hd * 2048 + qg) * 128 + s * 16 + h * 8);

  f32x16 po[4] = {};
  float mrow = -1e30f, lrow = 0.f;

  const int krow = tid >> 4;
  const int kcol = (tid & 15) * 16;
  const int vrow = tid >> 3;
  const int vcol = (tid & 7) * 16;

#define STAGE_KV(JT, BUF)                                                      \
  {                                                                            \
    _Pragma("unroll")                                                          \
    for (int ii = 0; ii < 4; ++ii) {                                           \
      int row = ii * 16 + krow;                                                \
      gload_lds16(Kbase + (size_t)((JT) * 64 + row) * 256 +                    \
                      (kcol ^ ((row & 7) << 4)),                               \
                  (char*)Ks[BUF] + row * 256 + kcol);                          \
    }                                                                          \
    _Pragma("unroll")                                                          \
    for (int ii = 0; ii < 4; ++ii) {                                           \
      int row = ii * 32 + vrow;                                                \
      gload_lds16(Vbase + (size_t)row * 4096 + (JT) * 128 +                    \
                      (vcol ^ ((row & 7) << 4)),                               \
                  (char*)Vs[BUF] + row * 128 + vcol);                          \
    }                                                                          \
  }

  STAGE_KV(0, 0)

  const int jmax = 2 * qb + 2;
  for (int j = 0; j < jmax; ++j) {
    const int cur = j & 1;
    const int jn = (j + 1 < jmax) ? j + 1 : j;
    STAGE_KV(jn, cur ^ 1)
    asm volatile("s_waitcnt vmcnt(8)" ::: "memory");
    __builtin_amdgcn_sched_barrier(0);
    __builtin_amdgcn_s_barrier();
    __builtin_amdgcn_sched_barrier(0);

    const unsigned short* Kc = Ks[cur];
    const unsigned short* Vc = Vs[cur];

    f32x16 sa[2] = {};
    __builtin_amdgcn_s_setprio(1);
#pragma unroll
    for (int ni = 0; ni < 2; ++ni) {
      const int row = ni * 32 + i5;
      const int swz = (row & 7) << 4;
#pragma unroll
      for (int s = 0; s < 8; ++s) {
        bf16x8 kf = *reinterpret_cast<const bf16x8*>(
            (const char*)Kc + ((row * 256 + s * 32 + h * 16) ^ swz));
        sa[ni] = MFMA32(kf, qf[s], sa[ni]);
      }
    }
    __builtin_amdgcn_s_setprio(0);

    if (j >= 2 * qb) {
#pragma unroll
      for (int ni = 0; ni < 2; ++ni) {
        const int kvb = j * 64 + ni * 32 + 4 * h;
#pragma unroll
        for (int r = 0; r < 16; ++r) {
          int kvg = kvb + (r & 3) + 8 * (r >> 2);
          if (kvg > qg) sa[ni][r] = -__builtin_inff();
        }
      }
    }

    float pmax = sa[0][0];
#pragma unroll
    for (int r = 1; r < 16; ++r) pmax = fmaxf(pmax, sa[0][r]);
#pragma unroll
    for (int r = 0; r < 16; ++r) pmax = fmaxf(pmax, sa[1][r]);
    pmax = fmaxf(pmax, __shfl_xor(pmax, 32));

    if (!__all(pmax <= mrow + 8.0f)) {
      float mnew = fmaxf(mrow, pmax);
      float sf = __expf(mrow - mnew);
#pragma unroll
      for (int d = 0; d < 4; ++d)
#pragma unroll
        for (int r = 0; r < 16; ++r) po[d][r] *= sf;
      lrow *= sf;
      mrow = mnew;
    }

    float rs = 0.f;
#pragma unroll
    for (int ni = 0; ni < 2; ++ni)
#pragma unroll
      for (int r = 0; r < 16; ++r) {
        float p = __expf(sa[ni][r] - mrow);
        sa[ni][r] = p;
        rs += p;
      }
    rs += __shfl_xor(rs, 32);
    lrow += rs;

    bf16x8 pfrag[4];
#pragma unroll
    for (int ni = 0; ni < 2; ++ni) {
      unsigned wd[8];
#pragma unroll
      for (int c = 0; c < 4; ++c)
#pragma unroll
        for (int ii = 0; ii < 2; ++ii)
          wd[c * 2 + ii] = (unsigned)f2b(sa[ni][4 * c + 2 * ii]) |
                           ((unsigned)f2b(sa[ni][4 * c + 2 * ii + 1]) << 16);
#pragma unroll
      for (int k2 = 0; k2 < 2; ++k2) {
        unsigned e0 = wd[(2 * k2) * 2 + 0], e1 = wd[(2 * k2) * 2 + 1];
        unsigned o0 = wd[(2 * k2 + 1) * 2 + 0], o1 = wd[(2 * k2 + 1) * 2 + 1];
        unsigned pe0 = (unsigned)__shfl_xor((int)e0, 32);
        unsigned pe1 = (unsigned)__shfl_xor((int)e1, 32);
        unsigned po0 = (unsigned)__shfl_xor((int)o0, 32);
        unsigned po1 = (unsigned)__shfl_xor((int)o1, 32);
        union { unsigned u[4]; bf16x8 v; } uu;
        uu.u[0] = h ? po0 : e0;
        uu.u[1] = h ? po1 : e1;
        uu.u[2] = h ? o0 : pe0;
        uu.u[3] = h ? o1 : pe1;
        pfrag[ni * 2 + k2] = uu.v;
      }
    }

    __builtin_amdgcn_s_setprio(1);
#pragma unroll
    for (int d = 0; d < 4; ++d) {
      const int row0 = d * 32 + i5;
      const int swz = (row0 & 7) << 4;
#pragma unroll
      for (int ks = 0; ks < 4; ++ks) {
        bf16x8 vf = *reinterpret_cast<const bf16x8*>(
            (const char*)Vc + ((row0 * 128 + ks * 32 + h * 16) ^ swz));
        po[d] = MFMA32(vf, pfrag[ks], po[d]);
      }
    }
    __builtin_amdgcn_s_setprio(0);

    __builtin_amdgcn_sched_barrier(0);
    __builtin_amdgcn_s_barrier();
    __builtin_amdgcn_sched_barrier(0);
  }
#undef STAGE_KV

  const float inv = 1.0f / lrow;
#pragma unroll
  for (int d = 0; d < 4; ++d)
#pragma unroll
    for (int c = 0; c < 4; ++c) {
      ushort4 st;
      st.x = f2b(po[d][4 * c + 0] * inv);
      st.y = f2b(po[d][4 * c + 1] * inv);
      st.z = f2b(po[d][4 * c + 2] * inv);
      st.w = f2b(po[d][4 * c + 3] * inv);
      *reinterpret_cast<ushort4*>(
          ctx + (size_t)qg * 4096 + hd * 128 + d * 32 + 8 * c + 4 * h) = st;
    }
}

// ---------- launch ----------
extern "C" void kernel_launch(void* const* d_in, const int* in_sizes, int n_in,
                              void* d_out, int out_size, void* d_ws, size_t ws_size,
                              hipStream_t stream) {
  const float* X    = (const float*)d_in[0];
  const float* cosb = (const float*)d_in[2];
  const float* sinb = (const float*)d_in[3];
  const float* Wq   = (const float*)d_in[4];
  const float* Wk   = (const float*)d_in[5];
  const float* Wv   = (const float*)d_in[6];
  const float* Wo   = (const float*)d_in[7];

  char* ws = (char*)d_ws;
  unsigned short* WT   = (unsigned short*)(ws + 0);           // 6144x4096 bf16 (later: WoT)
  unsigned short* Xb   = (unsigned short*)(ws + 50331648ull); // 2048x4096 bf16
  unsigned short* Cpre = (unsigned short*)(ws + 67108864ull); // 2048x6144 bf16 (later: ctx)
  unsigned short* Qr   = (unsigned short*)(ws + 92274688ull); // 32x2048x128 bf16
  unsigned short* Kr   = (unsigned short*)(ws + 109051904ull);// 8x2048x128 bf16
  unsigned short* Vt   = (unsigned short*)(ws + 113246208ull);// 8x128x2048 bf16
  unsigned short* ctx  = Cpre;

  k_transpose_qkv<<<dim3(64, 96), 256, 0, stream>>>(Wq, Wk, Wv, WT);
  k_f32_to_bf16<<<8192, 256, 0, stream>>>(X, Xb);

  // fused QKV projection: 128^2 tiles, BK=64, XCD-swizzled 1D grid (768)
  k_gemm<false><<<768, 256, 0, stream>>>(Xb, WT, Cpre, 2048, 6144, 4096);

  k_rope<<<dim3(2048, 20), 256, 0, stream>>>(Cpre, cosb, sinb, Qr, Kr);
  k_transpose_v<<<dim3(32, 2, 8), 256, 0, stream>>>(Cpre, Vt);

  k_transpose_f32_bf16<<<dim3(64, 64), 256, 0, stream>>>(Wo, WT, 4096, 4096);

  k_attn<<<512, 256, 0, stream>>>(Qr, Kr, Vt, ctx);

  // out projection: BK=64, XCD-swizzled 1D grid (512)
  k_gemm<true><<<512, 256, 0, stream>>>(ctx, WT, d_out, 2048, 4096, 4096);
}